// Round 2
// baseline (2114.797 us; speedup 1.0000x reference)
//
#include <hip/hip_runtime.h>

#define N_NODES 100000
#define N_EDGES 1600000

// ---------------- CSR build ----------------

__global__ void deg_kernel(const int* __restrict__ dst, int* __restrict__ deg, int e) {
    int i = blockIdx.x * blockDim.x + threadIdx.x;
    if (i < e) atomicAdd(&deg[dst[i]], 1);
}

// single-block exclusive scan (wave shfl scan + LDS wave sums)
__global__ __launch_bounds__(1024) void scan_kernel(const int* __restrict__ deg,
                                                    int* __restrict__ offs, int n) {
    __shared__ int wsum[16];
    __shared__ int carry;
    int t = threadIdx.x;
    int lane = t & 63, w = t >> 6;
    if (t == 0) carry = 0;
    __syncthreads();
    for (int start = 0; start < n; start += 1024) {
        int i = start + t;
        int v = (i < n) ? deg[i] : 0;
        int s = v;
        #pragma unroll
        for (int d = 1; d < 64; d <<= 1) {
            int u = __shfl_up(s, d, 64);
            if (lane >= d) s += u;
        }
        if (lane == 63) wsum[w] = s;
        __syncthreads();
        int wbase = 0;
        for (int j = 0; j < w; ++j) wbase += wsum[j];
        int base = carry;
        if (i < n) offs[i] = base + wbase + s - v;
        __syncthreads();
        if (t == 1023) carry = base + wbase + s;
        __syncthreads();
    }
    if (t == 0) offs[n] = carry;
}

__global__ void fill_csr(const int* __restrict__ src, const int* __restrict__ dst,
                         const int* __restrict__ offs, int* __restrict__ cursor,
                         int* __restrict__ csr, int e) {
    int i = blockIdx.x * blockDim.x + threadIdx.x;
    if (i < e) {
        int d = dst[i];
        int pos = offs[d] + atomicAdd(&cursor[d], 1);
        csr[pos] = src[i];
    }
}

// ---------------- mean aggregation: one wave per node ----------------

template <int D>
__global__ __launch_bounds__(256) void agg_kernel(const float* __restrict__ x,
                                                  const int* __restrict__ csr,
                                                  const int* __restrict__ offs,
                                                  float* __restrict__ agg, int n) {
    int node = blockIdx.x * 4 + (threadIdx.x >> 6);
    int lane = threadIdx.x & 63;
    if (node >= n) return;
    int e0 = offs[node], e1 = offs[node + 1];
    if constexpr (D == 256) {
        float4 acc = {0.f, 0.f, 0.f, 0.f};
        for (int e = e0; e < e1; ++e) {
            int s = csr[e];
            float4 f = ((const float4*)(x + (size_t)s * D))[lane];
            acc.x += f.x; acc.y += f.y; acc.z += f.z; acc.w += f.w;
        }
        float inv = 1.0f / fmaxf((float)(e1 - e0), 1.0f);
        acc.x *= inv; acc.y *= inv; acc.z *= inv; acc.w *= inv;
        ((float4*)(agg + (size_t)node * D))[lane] = acc;
    } else {
        float2 acc = {0.f, 0.f};
        for (int e = e0; e < e1; ++e) {
            int s = csr[e];
            float2 f = ((const float2*)(x + (size_t)s * D))[lane];
            acc.x += f.x; acc.y += f.y;
        }
        float inv = 1.0f / fmaxf((float)(e1 - e0), 1.0f);
        acc.x *= inv; acc.y *= inv;
        ((float2*)(agg + (size_t)node * D))[lane] = acc;
    }
}

// ---------------- fused full-row GEMM ----------------
// out[64 rows x dout] = A1@W1 + A2@W2 + b (+relu), one block per 64-row stripe.
// Because the block reads ONLY its own 64 rows of A1/A2 and writes the same
// rows, out may alias A1 (in-place layer 2): all global reads of those rows
// complete (barrier after tile load) before any epilogue store.
// NCOL = dout/16 rounded up; thread handles 4 rows x NCOL strided-16 cols.

template <int NCOL>
__global__ __launch_bounds__(256) void gemm_full(const float* __restrict__ A1,
                                                 const float* __restrict__ A2,
                                                 const float* __restrict__ W1,
                                                 const float* __restrict__ W2,
                                                 const float* __restrict__ bias,
                                                 float* __restrict__ out, int n, int K,
                                                 int dout, int relu) {
    __shared__ float As[16][64];
    __shared__ float Bs[16][NCOL * 16];
    const int t = threadIdx.x;
    const int bm = blockIdx.x * 64;
    const int tr = t >> 4;   // 0..15 -> rows tr*4..tr*4+3
    const int tc = t & 15;   // col lane
    float acc[4][NCOL];
    #pragma unroll
    for (int i = 0; i < 4; ++i)
        #pragma unroll
        for (int j = 0; j < NCOL; ++j) acc[i][j] = 0.f;

    for (int phase = 0; phase < 2; ++phase) {
        const float* __restrict__ A = phase ? A2 : A1;
        const float* __restrict__ W = phase ? W2 : W1;
        for (int k0 = 0; k0 < K; k0 += 16) {
            __syncthreads();  // protect LDS from previous iteration's readers
            // A tile: 64 rows x 16 cols (one float4 per thread)
            {
                int row = t >> 2;          // 0..63
                int c4 = (t & 3) << 2;     // 0,4,8,12
                int gr = bm + row;
                float4 v = {0.f, 0.f, 0.f, 0.f};
                if (gr < n) v = *(const float4*)(A + (size_t)gr * K + k0 + c4);
                As[c4 + 0][row] = v.x;
                As[c4 + 1][row] = v.y;
                As[c4 + 2][row] = v.z;
                As[c4 + 3][row] = v.w;
            }
            // B tile: 16 rows x dout cols; thread loads 16 consecutive cols
            {
                int row = t >> 4;          // 0..15
                int cb = (t & 15) << 4;    // 0,16,...,240
                if (cb < NCOL * 16) {
                    if constexpr (NCOL == 16) {
                        const float* wp = W + (size_t)(k0 + row) * dout + cb;
                        float4 v0 = ((const float4*)wp)[0];
                        float4 v1 = ((const float4*)wp)[1];
                        float4 v2 = ((const float4*)wp)[2];
                        float4 v3 = ((const float4*)wp)[3];
                        *(float4*)&Bs[row][cb + 0]  = v0;
                        *(float4*)&Bs[row][cb + 4]  = v1;
                        *(float4*)&Bs[row][cb + 8]  = v2;
                        *(float4*)&Bs[row][cb + 12] = v3;
                    } else {
                        const float* wp = W + (size_t)(k0 + row) * dout + cb;
                        #pragma unroll
                        for (int i2 = 0; i2 < 16; ++i2)
                            Bs[row][cb + i2] = (cb + i2 < dout) ? wp[i2] : 0.f;
                    }
                }
            }
            __syncthreads();
            #pragma unroll
            for (int kk = 0; kk < 16; ++kk) {
                float a[4], b[NCOL];
                #pragma unroll
                for (int i = 0; i < 4; ++i) a[i] = As[kk][tr * 4 + i];
                #pragma unroll
                for (int j = 0; j < NCOL; ++j) b[j] = Bs[kk][tc + 16 * j];
                #pragma unroll
                for (int i = 0; i < 4; ++i)
                    #pragma unroll
                    for (int j = 0; j < NCOL; ++j) acc[i][j] += a[i] * b[j];
            }
        }
    }

    #pragma unroll
    for (int i = 0; i < 4; ++i) {
        int gr = bm + tr * 4 + i;
        if (gr >= n) continue;
        #pragma unroll
        for (int j = 0; j < NCOL; ++j) {
            int gc = tc + 16 * j;
            if (gc >= dout) continue;
            float v = acc[i][j] + bias[gc];
            if (relu) v = fmaxf(v, 0.0f);
            out[(size_t)gr * dout + gc] = v;
        }
    }
}

extern "C" void kernel_launch(void* const* d_in, const int* in_sizes, int n_in,
                              void* d_out, int out_size, void* d_ws, size_t ws_size,
                              hipStream_t stream) {
    (void)in_sizes; (void)n_in; (void)out_size; (void)ws_size;
    const int N = N_NODES, E = N_EDGES;
    const float* x = (const float*)d_in[0];
    const int* src = (const int*)d_in[1];
    const int* dst = (const int*)d_in[2];
    const float* w_self1 = (const float*)d_in[3];
    const float* w_neigh1 = (const float*)d_in[4];
    const float* b1 = (const float*)d_in[5];
    const float* w_self2 = (const float*)d_in[6];
    const float* w_neigh2 = (const float*)d_in[7];
    const float* b2 = (const float*)d_in[8];
    const float* w_self3 = (const float*)d_in[9];
    const float* w_neigh3 = (const float*)d_in[10];
    const float* b3 = (const float*)d_in[11];
    float* out = (float*)d_out;

    // workspace layout (~212.5 MB total)
    float* P = (float*)d_ws;                     // N*256 (agg buffer; N*128 in L1)
    float* H = P + (size_t)N * 256;              // N*256 (hidden state)
    int* deg = (int*)(H + (size_t)N * 256);      // N
    int* offs = deg + N;                         // N+1
    int* cursor = offs + N + 1;                  // N
    int* csr = cursor + N;                       // E

    hipMemsetAsync(deg, 0, N * sizeof(int), stream);
    hipMemsetAsync(cursor, 0, N * sizeof(int), stream);

    deg_kernel<<<(E + 255) / 256, 256, 0, stream>>>(dst, deg, E);
    scan_kernel<<<1, 1024, 0, stream>>>(deg, offs, N);
    fill_csr<<<(E + 255) / 256, 256, 0, stream>>>(src, dst, offs, cursor, csr, E);

    int aggGrid = (N + 3) / 4;
    int gemmGrid = (N + 63) / 64;

    // layer 1: 128 -> 256, relu.  H = relu(x@Ws1 + P@Wn1 + b1)
    agg_kernel<128><<<aggGrid, 256, 0, stream>>>(x, csr, offs, P, N);
    gemm_full<16><<<gemmGrid, 256, 0, stream>>>(x, P, w_self1, w_neigh1, b1, H, N, 128, 256, 1);

    // layer 2: 256 -> 256, relu.  H = relu(H@Ws2 + P@Wn2 + b2)  (in place)
    agg_kernel<256><<<aggGrid, 256, 0, stream>>>(H, csr, offs, P, N);
    gemm_full<16><<<gemmGrid, 256, 0, stream>>>(H, P, w_self2, w_neigh2, b2, H, N, 256, 256, 1);

    // layer 3: 256 -> 47.  out = H@Ws3 + P@Wn3 + b3
    agg_kernel<256><<<aggGrid, 256, 0, stream>>>(H, csr, offs, P, N);
    gemm_full<3><<<gemmGrid, 256, 0, stream>>>(H, P, w_self3, w_neigh3, b3, out, N, 256, 47, 0);
}

// Round 3
// 1293.401 us; speedup vs baseline: 1.6351x; 1.6351x over previous
//
#include <hip/hip_runtime.h>

#define N_NODES 100000
#define N_EDGES 1600000

typedef __attribute__((ext_vector_type(8))) short short8;
typedef __attribute__((ext_vector_type(8))) unsigned short ushort8;
typedef __attribute__((ext_vector_type(4))) float floatx4;

// ---------------- bf16 split helpers ----------------

__device__ __forceinline__ unsigned short f2bf(float f) {
    unsigned int u = __float_as_uint(f);
    unsigned int r = (u + 0x7FFFu + ((u >> 16) & 1u)) >> 16;  // RN-even
    return (unsigned short)r;
}
__device__ __forceinline__ float bf2f(unsigned short h) {
    return __uint_as_float(((unsigned int)h) << 16);
}
__device__ __forceinline__ void cv2(float v, unsigned short& h, unsigned short& l) {
    h = f2bf(v);
    l = f2bf(v - bf2f(h));
}

// ---------------- CSR build ----------------

__global__ void deg_kernel(const int* __restrict__ dst, int* __restrict__ deg, int e) {
    int i = blockIdx.x * blockDim.x + threadIdx.x;
    if (i < e) atomicAdd(&deg[dst[i]], 1);
}

__global__ __launch_bounds__(1024) void scan_kernel(const int* __restrict__ deg,
                                                    int* __restrict__ offs, int n) {
    __shared__ int wsum[16];
    __shared__ int carry;
    int t = threadIdx.x;
    int lane = t & 63, w = t >> 6;
    if (t == 0) carry = 0;
    __syncthreads();
    for (int start = 0; start < n; start += 1024) {
        int i = start + t;
        int v = (i < n) ? deg[i] : 0;
        int s = v;
        #pragma unroll
        for (int d = 1; d < 64; d <<= 1) {
            int u = __shfl_up(s, d, 64);
            if (lane >= d) s += u;
        }
        if (lane == 63) wsum[w] = s;
        __syncthreads();
        int wbase = 0;
        for (int j = 0; j < w; ++j) wbase += wsum[j];
        int base = carry;
        if (i < n) offs[i] = base + wbase + s - v;
        __syncthreads();
        if (t == 1023) carry = base + wbase + s;
        __syncthreads();
    }
    if (t == 0) offs[n] = carry;
}

__global__ void fill_csr(const int* __restrict__ src, const int* __restrict__ dst,
                         const int* __restrict__ offs, int* __restrict__ cursor,
                         int* __restrict__ csr, int e) {
    int i = blockIdx.x * blockDim.x + threadIdx.x;
    if (i < e) {
        int d = dst[i];
        int pos = offs[d] + atomicAdd(&cursor[d], 1);
        csr[pos] = src[i];
    }
}

// ---------------- mean aggregation: one wave per node ----------------

template <int D>
__global__ __launch_bounds__(256) void agg_kernel(const float* __restrict__ x,
                                                  const int* __restrict__ csr,
                                                  const int* __restrict__ offs,
                                                  float* __restrict__ agg, int n) {
    int node = blockIdx.x * 4 + (threadIdx.x >> 6);
    int lane = threadIdx.x & 63;
    if (node >= n) return;
    int e0 = offs[node], e1 = offs[node + 1];
    if constexpr (D == 256) {
        float4 acc = {0.f, 0.f, 0.f, 0.f};
        for (int e = e0; e < e1; ++e) {
            int s = csr[e];
            float4 f = ((const float4*)(x + (size_t)s * D))[lane];
            acc.x += f.x; acc.y += f.y; acc.z += f.z; acc.w += f.w;
        }
        float inv = 1.0f / fmaxf((float)(e1 - e0), 1.0f);
        acc.x *= inv; acc.y *= inv; acc.z *= inv; acc.w *= inv;
        ((float4*)(agg + (size_t)node * D))[lane] = acc;
    } else {
        float2 acc = {0.f, 0.f};
        for (int e = e0; e < e1; ++e) {
            int s = csr[e];
            float2 f = ((const float2*)(x + (size_t)s * D))[lane];
            acc.x += f.x; acc.y += f.y;
        }
        float inv = 1.0f / fmaxf((float)(e1 - e0), 1.0f);
        acc.x *= inv; acc.y *= inv;
        ((float2*)(agg + (size_t)node * D))[lane] = acc;
    }
}

// ---------------- weight prep: W[K][dout] fp32 -> Wt_hi/lo[npad][K] bf16 ----------------

__global__ void prep_w(const float* __restrict__ W, unsigned short* __restrict__ hi,
                       unsigned short* __restrict__ lo, int kshift, int K, int dout,
                       int npad) {
    int i = blockIdx.x * blockDim.x + threadIdx.x;
    if (i >= npad * K) return;
    int n_idx = i >> kshift;
    int k = i & (K - 1);
    float v = (n_idx < dout) ? W[(size_t)k * dout + n_idx] : 0.f;
    unsigned short h, l;
    cv2(v, h, l);
    hi[i] = h;
    lo[i] = l;
}

// ---------------- MFMA GEMM: out[128 x dout] = A1@W1 + A2@W2 + b (+relu) ----------------
// Split-bf16: A=Ahi+Alo, W=Whi+Wlo; C ~= AhiWhi + AloWhi + AhiWlo (3 MFMA / tile).
// One block per 128-row stripe, full dout per block => block touches only its own
// rows of A1/out, so out may alias A1 (in-place layer 2).
// Frag layouts (m89/m91-verified): A[m=lane&15][k=quad*8+j]; B from Wt[n][k]
// (contiguous k) ; D: col=lane&15, row=quad*4+reg.
// LDS row stride 40 ushorts (80 B): 16-row b128 frag reads tile all 32 banks.

template <int NTILES>
__global__ __launch_bounds__(256, 2) void gemm_mfma(
    const float* __restrict__ A1, const float* __restrict__ A2,
    const unsigned short* __restrict__ W1h, const unsigned short* __restrict__ W1l,
    const unsigned short* __restrict__ W2h, const unsigned short* __restrict__ W2l,
    const float* __restrict__ bias, float* __restrict__ out, int n, int K, int dout,
    int relu) {
    constexpr int NPAD = NTILES * 16;
    constexpr int LDT = 40;
    __shared__ unsigned short As_h[128 * LDT];
    __shared__ unsigned short As_l[128 * LDT];
    __shared__ unsigned short Bs_h[NPAD * LDT];
    __shared__ unsigned short Bs_l[NPAD * LDT];

    const int t = threadIdx.x;
    const int bm = blockIdx.x * 128;
    const int lane = t & 63;
    const int w = t >> 6;
    const int quad = lane >> 4;
    const int tl = lane & 15;
    const int mw = w * 32;

    floatx4 acc[2][NTILES];
    #pragma unroll
    for (int i = 0; i < 2; ++i)
        #pragma unroll
        for (int j = 0; j < NTILES; ++j) acc[i][j] = (floatx4){0.f, 0.f, 0.f, 0.f};

    const int arow = t >> 1;          // 0..127
    const int acol = (t & 1) << 4;    // 0 or 16

    for (int phase = 0; phase < 2; ++phase) {
        const float* __restrict__ A = phase ? A2 : A1;
        const unsigned short* __restrict__ Wh = phase ? W2h : W1h;
        const unsigned short* __restrict__ Wl = phase ? W2l : W1l;
        for (int k0 = 0; k0 < K; k0 += 32) {
            __syncthreads();
            // ---- stage A (fp32 -> hi/lo bf16) ----
            {
                float f[16];
                if (bm + arow < n) {
                    const float4* ap =
                        (const float4*)(A + (size_t)(bm + arow) * K + k0 + acol);
                    float4 v0 = ap[0], v1 = ap[1], v2 = ap[2], v3 = ap[3];
                    f[0] = v0.x; f[1] = v0.y; f[2] = v0.z; f[3] = v0.w;
                    f[4] = v1.x; f[5] = v1.y; f[6] = v1.z; f[7] = v1.w;
                    f[8] = v2.x; f[9] = v2.y; f[10] = v2.z; f[11] = v2.w;
                    f[12] = v3.x; f[13] = v3.y; f[14] = v3.z; f[15] = v3.w;
                } else {
                    #pragma unroll
                    for (int j = 0; j < 16; ++j) f[j] = 0.f;
                }
                ushort8 h0, l0, h1, l1;
                #pragma unroll
                for (int j = 0; j < 8; ++j) {
                    unsigned short hh, ll;
                    cv2(f[j], hh, ll);
                    h0[j] = hh; l0[j] = ll;
                    cv2(f[8 + j], hh, ll);
                    h1[j] = hh; l1[j] = ll;
                }
                *(ushort8*)&As_h[arow * LDT + acol] = h0;
                *(ushort8*)&As_h[arow * LDT + acol + 8] = h1;
                *(ushort8*)&As_l[arow * LDT + acol] = l0;
                *(ushort8*)&As_l[arow * LDT + acol + 8] = l1;
            }
            // ---- stage B (already bf16, [n][k] layout) ----
            if (t < NPAD) {
                const ushort8* sh = (const ushort8*)(Wh + (size_t)t * K + k0);
                const ushort8* sl = (const ushort8*)(Wl + (size_t)t * K + k0);
                ushort8 b0 = sh[0], b1 = sh[1], b2 = sh[2], b3 = sh[3];
                ushort8 c0 = sl[0], c1 = sl[1], c2 = sl[2], c3 = sl[3];
                *(ushort8*)&Bs_h[t * LDT + 0] = b0;
                *(ushort8*)&Bs_h[t * LDT + 8] = b1;
                *(ushort8*)&Bs_h[t * LDT + 16] = b2;
                *(ushort8*)&Bs_h[t * LDT + 24] = b3;
                *(ushort8*)&Bs_l[t * LDT + 0] = c0;
                *(ushort8*)&Bs_l[t * LDT + 8] = c1;
                *(ushort8*)&Bs_l[t * LDT + 16] = c2;
                *(ushort8*)&Bs_l[t * LDT + 24] = c3;
            }
            __syncthreads();
            // ---- compute ----
            short8 ah0 = *(const short8*)&As_h[(mw + tl) * LDT + quad * 8];
            short8 ah1 = *(const short8*)&As_h[(mw + 16 + tl) * LDT + quad * 8];
            short8 al0 = *(const short8*)&As_l[(mw + tl) * LDT + quad * 8];
            short8 al1 = *(const short8*)&As_l[(mw + 16 + tl) * LDT + quad * 8];
            #pragma unroll
            for (int nt = 0; nt < NTILES; ++nt) {
                short8 bh = *(const short8*)&Bs_h[(nt * 16 + tl) * LDT + quad * 8];
                short8 bl = *(const short8*)&Bs_l[(nt * 16 + tl) * LDT + quad * 8];
                acc[0][nt] = __builtin_amdgcn_mfma_f32_16x16x32_bf16(ah0, bh, acc[0][nt], 0, 0, 0);
                acc[1][nt] = __builtin_amdgcn_mfma_f32_16x16x32_bf16(ah1, bh, acc[1][nt], 0, 0, 0);
                acc[0][nt] = __builtin_amdgcn_mfma_f32_16x16x32_bf16(al0, bh, acc[0][nt], 0, 0, 0);
                acc[1][nt] = __builtin_amdgcn_mfma_f32_16x16x32_bf16(al1, bh, acc[1][nt], 0, 0, 0);
                acc[0][nt] = __builtin_amdgcn_mfma_f32_16x16x32_bf16(ah0, bl, acc[0][nt], 0, 0, 0);
                acc[1][nt] = __builtin_amdgcn_mfma_f32_16x16x32_bf16(ah1, bl, acc[1][nt], 0, 0, 0);
            }
        }
    }
    // ---- epilogue ----
    #pragma unroll
    for (int mt = 0; mt < 2; ++mt) {
        #pragma unroll
        for (int nt = 0; nt < NTILES; ++nt) {
            int gc = nt * 16 + tl;
            if (gc >= dout) continue;
            float bv = bias[gc];
            #pragma unroll
            for (int r = 0; r < 4; ++r) {
                int gr = bm + mw + mt * 16 + quad * 4 + r;
                if (gr >= n) continue;
                float v = acc[mt][nt][r] + bv;
                if (relu) v = fmaxf(v, 0.f);
                out[(size_t)gr * dout + gc] = v;
            }
        }
    }
}

extern "C" void kernel_launch(void* const* d_in, const int* in_sizes, int n_in,
                              void* d_out, int out_size, void* d_ws, size_t ws_size,
                              hipStream_t stream) {
    (void)in_sizes; (void)n_in; (void)out_size; (void)ws_size;
    const int N = N_NODES, E = N_EDGES;
    const float* x = (const float*)d_in[0];
    const int* src = (const int*)d_in[1];
    const int* dst = (const int*)d_in[2];
    const float* w_self1 = (const float*)d_in[3];
    const float* w_neigh1 = (const float*)d_in[4];
    const float* b1 = (const float*)d_in[5];
    const float* w_self2 = (const float*)d_in[6];
    const float* w_neigh2 = (const float*)d_in[7];
    const float* b2 = (const float*)d_in[8];
    const float* w_self3 = (const float*)d_in[9];
    const float* w_neigh3 = (const float*)d_in[10];
    const float* b3 = (const float*)d_in[11];
    float* out = (float*)d_out;

    // workspace layout (~213 MB)
    float* P = (float*)d_ws;                  // N*256 (agg; N*128 in L1)
    float* H = P + (size_t)N * 256;           // N*256 (hidden; L2 in-place)
    int* deg = (int*)(H + (size_t)N * 256);   // N   (reused as cursor)
    int* offs = deg + N;                      // N+4 (padded for 16B alignment)
    int* csr = offs + N + 4;                  // E
    unsigned short* wq = (unsigned short*)(csr + E);
    unsigned short* w1sh = wq;                 // 256*128 each
    unsigned short* w1sl = w1sh + 32768;
    unsigned short* w1nh = w1sl + 32768;
    unsigned short* w1nl = w1nh + 32768;
    unsigned short* w2sh = w1nl + 32768;       // 256*256 each
    unsigned short* w2sl = w2sh + 65536;
    unsigned short* w2nh = w2sl + 65536;
    unsigned short* w2nl = w2nh + 65536;
    unsigned short* w3sh = w2nl + 65536;       // 48*256 each
    unsigned short* w3sl = w3sh + 12288;
    unsigned short* w3nh = w3sl + 12288;
    unsigned short* w3nl = w3nh + 12288;

    hipMemsetAsync(deg, 0, N * sizeof(int), stream);
    deg_kernel<<<(E + 255) / 256, 256, 0, stream>>>(dst, deg, E);
    scan_kernel<<<1, 1024, 0, stream>>>(deg, offs, N);
    hipMemsetAsync(deg, 0, N * sizeof(int), stream);  // reuse deg as fill cursor
    fill_csr<<<(E + 255) / 256, 256, 0, stream>>>(src, dst, offs, deg, csr, E);

    // weight preprocessing (transpose + bf16 hi/lo split)
    prep_w<<<(256 * 128 + 255) / 256, 256, 0, stream>>>(w_self1, w1sh, w1sl, 7, 128, 256, 256);
    prep_w<<<(256 * 128 + 255) / 256, 256, 0, stream>>>(w_neigh1, w1nh, w1nl, 7, 128, 256, 256);
    prep_w<<<(256 * 256 + 255) / 256, 256, 0, stream>>>(w_self2, w2sh, w2sl, 8, 256, 256, 256);
    prep_w<<<(256 * 256 + 255) / 256, 256, 0, stream>>>(w_neigh2, w2nh, w2nl, 8, 256, 256, 256);
    prep_w<<<(48 * 256 + 255) / 256, 256, 0, stream>>>(w_self3, w3sh, w3sl, 8, 256, 47, 48);
    prep_w<<<(48 * 256 + 255) / 256, 256, 0, stream>>>(w_neigh3, w3nh, w3nl, 8, 256, 47, 48);

    int aggGrid = (N + 3) / 4;
    int gemmGrid = (N + 127) / 128;

    // layer 1: 128 -> 256, relu.  H = relu(x@Ws1 + P@Wn1 + b1)
    agg_kernel<128><<<aggGrid, 256, 0, stream>>>(x, csr, offs, P, N);
    gemm_mfma<16><<<gemmGrid, 256, 0, stream>>>(x, P, w1sh, w1sl, w1nh, w1nl, b1, H, N, 128,
                                                256, 1);
    // layer 2: 256 -> 256, relu.  H = relu(H@Ws2 + P@Wn2 + b2)  (in place)
    agg_kernel<256><<<aggGrid, 256, 0, stream>>>(H, csr, offs, P, N);
    gemm_mfma<16><<<gemmGrid, 256, 0, stream>>>(H, P, w2sh, w2sl, w2nh, w2nl, b2, H, N, 256,
                                                256, 1);
    // layer 3: 256 -> 47.  out = H@Ws3 + P@Wn3 + b3
    agg_kernel<256><<<aggGrid, 256, 0, stream>>>(H, csr, offs, P, N);
    gemm_mfma<3><<<gemmGrid, 256, 0, stream>>>(H, P, w3sh, w3sl, w3nh, w3nl, b3, out, N, 256,
                                               47, 0);
}

// Round 4
// 1073.204 us; speedup vs baseline: 1.9705x; 1.2052x over previous
//
#include <hip/hip_runtime.h>

#define N_NODES 100000
#define N_EDGES 1600000

typedef __attribute__((ext_vector_type(8))) short short8;
typedef __attribute__((ext_vector_type(8))) unsigned short ushort8;
typedef __attribute__((ext_vector_type(4))) float floatx4;

// ---------------- bf16 split helpers ----------------

__device__ __forceinline__ unsigned short f2bf(float f) {
    unsigned int u = __float_as_uint(f);
    unsigned int r = (u + 0x7FFFu + ((u >> 16) & 1u)) >> 16;  // RN-even
    return (unsigned short)r;
}
__device__ __forceinline__ float bf2f(unsigned short h) {
    return __uint_as_float(((unsigned int)h) << 16);
}
__device__ __forceinline__ void cv2(float v, unsigned short& h, unsigned short& l) {
    h = f2bf(v);
    l = f2bf(v - bf2f(h));
}

// ---------------- CSR build ----------------

__global__ void deg_kernel(const int* __restrict__ dst, int* __restrict__ deg, int e) {
    int i = blockIdx.x * blockDim.x + threadIdx.x;
    if (i < e) atomicAdd(&deg[dst[i]], 1);
}

__global__ __launch_bounds__(1024) void scan_kernel(const int* __restrict__ deg,
                                                    int* __restrict__ offs, int n) {
    __shared__ int wsum[16];
    __shared__ int carry;
    int t = threadIdx.x;
    int lane = t & 63, w = t >> 6;
    if (t == 0) carry = 0;
    __syncthreads();
    for (int start = 0; start < n; start += 1024) {
        int i = start + t;
        int v = (i < n) ? deg[i] : 0;
        int s = v;
        #pragma unroll
        for (int d = 1; d < 64; d <<= 1) {
            int u = __shfl_up(s, d, 64);
            if (lane >= d) s += u;
        }
        if (lane == 63) wsum[w] = s;
        __syncthreads();
        int wbase = 0;
        for (int j = 0; j < w; ++j) wbase += wsum[j];
        int base = carry;
        if (i < n) offs[i] = base + wbase + s - v;
        __syncthreads();
        if (t == 1023) carry = base + wbase + s;
        __syncthreads();
    }
    if (t == 0) offs[n] = carry;
}

__global__ void fill_csr(const int* __restrict__ src, const int* __restrict__ dst,
                         const int* __restrict__ offs, int* __restrict__ cursor,
                         int* __restrict__ csr, int e) {
    int i = blockIdx.x * blockDim.x + threadIdx.x;
    if (i < e) {
        int d = dst[i];
        int pos = offs[d] + atomicAdd(&cursor[d], 1);
        csr[pos] = src[i];
    }
}

// ---------------- mean aggregation, MLP-unrolled ----------------
// Index batch: one coalesced csr load per LPN edges, then __shfl broadcast;
// 4 independent row-gathers per inner iteration for memory-level parallelism.

// D=256: one wave (64 lanes) per node, float4/lane.
__global__ __launch_bounds__(256) void agg256(const float* __restrict__ x,
                                              const int* __restrict__ csr,
                                              const int* __restrict__ offs,
                                              float* __restrict__ agg, int n) {
    int node = blockIdx.x * 4 + (threadIdx.x >> 6);
    int lane = threadIdx.x & 63;
    if (node >= n) return;
    int e0 = offs[node], e1 = offs[node + 1];
    float4 acc = {0.f, 0.f, 0.f, 0.f};
    for (int e = e0; e < e1;) {
        int take = e1 - e;
        if (take > 64) take = 64;
        int idx = csr[e + (lane < take ? lane : 0)];
        int j = 0;
        for (; j + 4 <= take; j += 4) {
            int s0 = __shfl(idx, j, 64);
            int s1 = __shfl(idx, j + 1, 64);
            int s2 = __shfl(idx, j + 2, 64);
            int s3 = __shfl(idx, j + 3, 64);
            float4 f0 = ((const float4*)(x + (size_t)s0 * 256))[lane];
            float4 f1 = ((const float4*)(x + (size_t)s1 * 256))[lane];
            float4 f2 = ((const float4*)(x + (size_t)s2 * 256))[lane];
            float4 f3 = ((const float4*)(x + (size_t)s3 * 256))[lane];
            acc.x += (f0.x + f1.x) + (f2.x + f3.x);
            acc.y += (f0.y + f1.y) + (f2.y + f3.y);
            acc.z += (f0.z + f1.z) + (f2.z + f3.z);
            acc.w += (f0.w + f1.w) + (f2.w + f3.w);
        }
        for (; j < take; ++j) {
            int s = __shfl(idx, j, 64);
            float4 f = ((const float4*)(x + (size_t)s * 256))[lane];
            acc.x += f.x; acc.y += f.y; acc.z += f.z; acc.w += f.w;
        }
        e += take;
    }
    float inv = 1.0f / fmaxf((float)(e1 - e0), 1.0f);
    acc.x *= inv; acc.y *= inv; acc.z *= inv; acc.w *= inv;
    ((float4*)(agg + (size_t)node * 256))[lane] = acc;
}

// D=128: 32-lane half-wave per node, float4/lane.
__global__ __launch_bounds__(256) void agg128(const float* __restrict__ x,
                                              const int* __restrict__ csr,
                                              const int* __restrict__ offs,
                                              float* __restrict__ agg, int n) {
    int node = blockIdx.x * 8 + (threadIdx.x >> 5);
    int sl = threadIdx.x & 31;
    if (node >= n) return;
    int e0 = offs[node], e1 = offs[node + 1];
    float4 acc = {0.f, 0.f, 0.f, 0.f};
    for (int e = e0; e < e1;) {
        int take = e1 - e;
        if (take > 32) take = 32;
        int idx = csr[e + (sl < take ? sl : 0)];
        int j = 0;
        for (; j + 4 <= take; j += 4) {
            int s0 = __shfl(idx, j, 32);
            int s1 = __shfl(idx, j + 1, 32);
            int s2 = __shfl(idx, j + 2, 32);
            int s3 = __shfl(idx, j + 3, 32);
            float4 f0 = ((const float4*)(x + (size_t)s0 * 128))[sl];
            float4 f1 = ((const float4*)(x + (size_t)s1 * 128))[sl];
            float4 f2 = ((const float4*)(x + (size_t)s2 * 128))[sl];
            float4 f3 = ((const float4*)(x + (size_t)s3 * 128))[sl];
            acc.x += (f0.x + f1.x) + (f2.x + f3.x);
            acc.y += (f0.y + f1.y) + (f2.y + f3.y);
            acc.z += (f0.z + f1.z) + (f2.z + f3.z);
            acc.w += (f0.w + f1.w) + (f2.w + f3.w);
        }
        for (; j < take; ++j) {
            int s = __shfl(idx, j, 32);
            float4 f = ((const float4*)(x + (size_t)s * 128))[sl];
            acc.x += f.x; acc.y += f.y; acc.z += f.z; acc.w += f.w;
        }
        e += take;
    }
    float inv = 1.0f / fmaxf((float)(e1 - e0), 1.0f);
    acc.x *= inv; acc.y *= inv; acc.z *= inv; acc.w *= inv;
    ((float4*)(agg + (size_t)node * 128))[sl] = acc;
}

// Layer-3 finish: out[node][0:47] = S[node] + mean_{s in nbrs}(Y[s]).
// 16-lane group per node; Y,S rows stride 48 floats (16B aligned); out stride 47.
__global__ __launch_bounds__(256) void agg_l3(const float* __restrict__ Y,
                                              const float* __restrict__ S,
                                              const int* __restrict__ csr,
                                              const int* __restrict__ offs,
                                              float* __restrict__ out, int n) {
    int node = blockIdx.x * 16 + (threadIdx.x >> 4);
    int sl = threadIdx.x & 15;
    if (node >= n) return;
    int c = sl < 12 ? sl : 11;  // lanes 12-15 duplicate lane 11 (never stored)
    int e0 = offs[node], e1 = offs[node + 1];
    float4 acc = {0.f, 0.f, 0.f, 0.f};
    for (int e = e0; e < e1;) {
        int take = e1 - e;
        if (take > 16) take = 16;
        int idx = csr[e + (sl < take ? sl : 0)];
        int j = 0;
        for (; j + 4 <= take; j += 4) {
            int s0 = __shfl(idx, j, 16);
            int s1 = __shfl(idx, j + 1, 16);
            int s2 = __shfl(idx, j + 2, 16);
            int s3 = __shfl(idx, j + 3, 16);
            float4 f0 = ((const float4*)(Y + (size_t)s0 * 48))[c];
            float4 f1 = ((const float4*)(Y + (size_t)s1 * 48))[c];
            float4 f2 = ((const float4*)(Y + (size_t)s2 * 48))[c];
            float4 f3 = ((const float4*)(Y + (size_t)s3 * 48))[c];
            acc.x += (f0.x + f1.x) + (f2.x + f3.x);
            acc.y += (f0.y + f1.y) + (f2.y + f3.y);
            acc.z += (f0.z + f1.z) + (f2.z + f3.z);
            acc.w += (f0.w + f1.w) + (f2.w + f3.w);
        }
        for (; j < take; ++j) {
            int s = __shfl(idx, j, 16);
            float4 f = ((const float4*)(Y + (size_t)s * 48))[c];
            acc.x += f.x; acc.y += f.y; acc.z += f.z; acc.w += f.w;
        }
        e += take;
    }
    float inv = 1.0f / fmaxf((float)(e1 - e0), 1.0f);
    float4 sv = ((const float4*)(S + (size_t)node * 48))[c];
    float r[4] = {sv.x + acc.x * inv, sv.y + acc.y * inv, sv.z + acc.z * inv,
                  sv.w + acc.w * inv};
    if (sl < 12) {
        #pragma unroll
        for (int k = 0; k < 4; ++k) {
            int col = c * 4 + k;
            if (col < 47) out[(size_t)node * 47 + col] = r[k];
        }
    }
}

// ---------------- weight prep: W[K][dout] fp32 -> Wt_hi/lo[npad][K] bf16 ----------------

__global__ void prep_w(const float* __restrict__ W, unsigned short* __restrict__ hi,
                       unsigned short* __restrict__ lo, int kshift, int K, int dout,
                       int npad) {
    int i = blockIdx.x * blockDim.x + threadIdx.x;
    if (i >= npad * K) return;
    int n_idx = i >> kshift;
    int k = i & (K - 1);
    float v = (n_idx < dout) ? W[(size_t)k * dout + n_idx] : 0.f;
    unsigned short h, l;
    cv2(v, h, l);
    hi[i] = h;
    lo[i] = l;
}

// ---------------- MFMA GEMM (split-bf16, fp32-accurate) ----------------
// out[128 x dout] = A1@W1 (+ A2@W2 if phases==2) + b (+relu).
// split mode: cols 0-47 -> S (stride 48, +bias, no relu), cols 48-95 -> Y (stride 48).

template <int NTILES>
__global__ __launch_bounds__(256, 2) void gemm_mfma(
    const float* __restrict__ A1, const float* __restrict__ A2,
    const unsigned short* __restrict__ W1h, const unsigned short* __restrict__ W1l,
    const unsigned short* __restrict__ W2h, const unsigned short* __restrict__ W2l,
    const float* __restrict__ bias, float* __restrict__ out, float* __restrict__ out2,
    int n, int K, int dout, int relu, int phases, int split) {
    constexpr int NPAD = NTILES * 16;
    constexpr int LDT = 40;
    __shared__ unsigned short As_h[128 * LDT];
    __shared__ unsigned short As_l[128 * LDT];
    __shared__ unsigned short Bs_h[NPAD * LDT];
    __shared__ unsigned short Bs_l[NPAD * LDT];

    const int t = threadIdx.x;
    const int bm = blockIdx.x * 128;
    const int lane = t & 63;
    const int w = t >> 6;
    const int quad = lane >> 4;
    const int tl = lane & 15;
    const int mw = w * 32;

    floatx4 acc[2][NTILES];
    #pragma unroll
    for (int i = 0; i < 2; ++i)
        #pragma unroll
        for (int j = 0; j < NTILES; ++j) acc[i][j] = (floatx4){0.f, 0.f, 0.f, 0.f};

    const int arow = t >> 1;
    const int acol = (t & 1) << 4;

    for (int phase = 0; phase < phases; ++phase) {
        const float* __restrict__ A = phase ? A2 : A1;
        const unsigned short* __restrict__ Wh = phase ? W2h : W1h;
        const unsigned short* __restrict__ Wl = phase ? W2l : W1l;
        for (int k0 = 0; k0 < K; k0 += 32) {
            __syncthreads();
            {
                float f[16];
                if (bm + arow < n) {
                    const float4* ap =
                        (const float4*)(A + (size_t)(bm + arow) * K + k0 + acol);
                    float4 v0 = ap[0], v1 = ap[1], v2 = ap[2], v3 = ap[3];
                    f[0] = v0.x; f[1] = v0.y; f[2] = v0.z; f[3] = v0.w;
                    f[4] = v1.x; f[5] = v1.y; f[6] = v1.z; f[7] = v1.w;
                    f[8] = v2.x; f[9] = v2.y; f[10] = v2.z; f[11] = v2.w;
                    f[12] = v3.x; f[13] = v3.y; f[14] = v3.z; f[15] = v3.w;
                } else {
                    #pragma unroll
                    for (int j = 0; j < 16; ++j) f[j] = 0.f;
                }
                ushort8 h0, l0, h1, l1;
                #pragma unroll
                for (int j = 0; j < 8; ++j) {
                    unsigned short hh, ll;
                    cv2(f[j], hh, ll);
                    h0[j] = hh; l0[j] = ll;
                    cv2(f[8 + j], hh, ll);
                    h1[j] = hh; l1[j] = ll;
                }
                *(ushort8*)&As_h[arow * LDT + acol] = h0;
                *(ushort8*)&As_h[arow * LDT + acol + 8] = h1;
                *(ushort8*)&As_l[arow * LDT + acol] = l0;
                *(ushort8*)&As_l[arow * LDT + acol + 8] = l1;
            }
            if (t < NPAD) {
                const ushort8* sh = (const ushort8*)(Wh + (size_t)t * K + k0);
                const ushort8* sl2 = (const ushort8*)(Wl + (size_t)t * K + k0);
                ushort8 b0 = sh[0], b1 = sh[1], b2 = sh[2], b3 = sh[3];
                ushort8 c0 = sl2[0], c1 = sl2[1], c2 = sl2[2], c3 = sl2[3];
                *(ushort8*)&Bs_h[t * LDT + 0] = b0;
                *(ushort8*)&Bs_h[t * LDT + 8] = b1;
                *(ushort8*)&Bs_h[t * LDT + 16] = b2;
                *(ushort8*)&Bs_h[t * LDT + 24] = b3;
                *(ushort8*)&Bs_l[t * LDT + 0] = c0;
                *(ushort8*)&Bs_l[t * LDT + 8] = c1;
                *(ushort8*)&Bs_l[t * LDT + 16] = c2;
                *(ushort8*)&Bs_l[t * LDT + 24] = c3;
            }
            __syncthreads();
            short8 ah0 = *(const short8*)&As_h[(mw + tl) * LDT + quad * 8];
            short8 ah1 = *(const short8*)&As_h[(mw + 16 + tl) * LDT + quad * 8];
            short8 al0 = *(const short8*)&As_l[(mw + tl) * LDT + quad * 8];
            short8 al1 = *(const short8*)&As_l[(mw + 16 + tl) * LDT + quad * 8];
            #pragma unroll
            for (int nt = 0; nt < NTILES; ++nt) {
                short8 bh = *(const short8*)&Bs_h[(nt * 16 + tl) * LDT + quad * 8];
                short8 bl = *(const short8*)&Bs_l[(nt * 16 + tl) * LDT + quad * 8];
                acc[0][nt] = __builtin_amdgcn_mfma_f32_16x16x32_bf16(ah0, bh, acc[0][nt], 0, 0, 0);
                acc[1][nt] = __builtin_amdgcn_mfma_f32_16x16x32_bf16(ah1, bh, acc[1][nt], 0, 0, 0);
                acc[0][nt] = __builtin_amdgcn_mfma_f32_16x16x32_bf16(al0, bh, acc[0][nt], 0, 0, 0);
                acc[1][nt] = __builtin_amdgcn_mfma_f32_16x16x32_bf16(al1, bh, acc[1][nt], 0, 0, 0);
                acc[0][nt] = __builtin_amdgcn_mfma_f32_16x16x32_bf16(ah0, bl, acc[0][nt], 0, 0, 0);
                acc[1][nt] = __builtin_amdgcn_mfma_f32_16x16x32_bf16(ah1, bl, acc[1][nt], 0, 0, 0);
            }
        }
    }
    #pragma unroll
    for (int mt = 0; mt < 2; ++mt) {
        #pragma unroll
        for (int nt = 0; nt < NTILES; ++nt) {
            int gc = nt * 16 + tl;
            if (!split && gc >= dout) continue;
            #pragma unroll
            for (int r = 0; r < 4; ++r) {
                int gr = bm + mw + mt * 16 + quad * 4 + r;
                if (gr >= n) continue;
                float v = acc[mt][nt][r];
                if (split) {
                    if (gc < 48) {
                        v += (gc < 47) ? bias[gc] : 0.f;
                        out[(size_t)gr * 48 + gc] = v;
                    } else {
                        out2[(size_t)gr * 48 + (gc - 48)] = v;
                    }
                } else {
                    v += bias[gc];
                    if (relu) v = fmaxf(v, 0.f);
                    out[(size_t)gr * dout + gc] = v;
                }
            }
        }
    }
}

extern "C" void kernel_launch(void* const* d_in, const int* in_sizes, int n_in,
                              void* d_out, int out_size, void* d_ws, size_t ws_size,
                              hipStream_t stream) {
    (void)in_sizes; (void)n_in; (void)out_size; (void)ws_size;
    const int N = N_NODES, E = N_EDGES;
    const float* x = (const float*)d_in[0];
    const int* src = (const int*)d_in[1];
    const int* dst = (const int*)d_in[2];
    const float* w_self1 = (const float*)d_in[3];
    const float* w_neigh1 = (const float*)d_in[4];
    const float* b1 = (const float*)d_in[5];
    const float* w_self2 = (const float*)d_in[6];
    const float* w_neigh2 = (const float*)d_in[7];
    const float* b2 = (const float*)d_in[8];
    const float* w_self3 = (const float*)d_in[9];
    const float* w_neigh3 = (const float*)d_in[10];
    const float* b3 = (const float*)d_in[11];
    float* out = (float*)d_out;

    // workspace layout (~213 MB)
    float* P = (float*)d_ws;                  // N*256 (agg; also Y/S for L3)
    float* H = P + (size_t)N * 256;           // N*256 (hidden; L2 in-place)
    int* deg = (int*)(H + (size_t)N * 256);   // N (reused as cursor)
    int* offs = deg + N;                      // N+4
    int* csr = offs + N + 4;                  // E
    unsigned short* wq = (unsigned short*)(csr + E);
    unsigned short* w1sh = wq;                 // 256*128 each
    unsigned short* w1sl = w1sh + 32768;
    unsigned short* w1nh = w1sl + 32768;
    unsigned short* w1nl = w1nh + 32768;
    unsigned short* w2sh = w1nl + 32768;       // 256*256 each
    unsigned short* w2sl = w2sh + 65536;
    unsigned short* w2nh = w2sl + 65536;
    unsigned short* w2nl = w2nh + 65536;
    unsigned short* w3ch = w2nl + 65536;       // combined [96][256] hi: self | neigh
    unsigned short* w3cl = w3ch + 24576;       // combined lo
    // L3 dual outputs overlay P (P free after L2 gemm consumes it)
    float* Y = P;                              // N*48
    float* S = P + (size_t)N * 48;             // N*48

    hipMemsetAsync(deg, 0, N * sizeof(int), stream);
    deg_kernel<<<(E + 255) / 256, 256, 0, stream>>>(dst, deg, E);
    scan_kernel<<<1, 1024, 0, stream>>>(deg, offs, N);
    hipMemsetAsync(deg, 0, N * sizeof(int), stream);
    fill_csr<<<(E + 255) / 256, 256, 0, stream>>>(src, dst, offs, deg, csr, E);

    prep_w<<<(256 * 128 + 255) / 256, 256, 0, stream>>>(w_self1, w1sh, w1sl, 7, 128, 256, 256);
    prep_w<<<(256 * 128 + 255) / 256, 256, 0, stream>>>(w_neigh1, w1nh, w1nl, 7, 128, 256, 256);
    prep_w<<<(256 * 256 + 255) / 256, 256, 0, stream>>>(w_self2, w2sh, w2sl, 8, 256, 256, 256);
    prep_w<<<(256 * 256 + 255) / 256, 256, 0, stream>>>(w_neigh2, w2nh, w2nl, 8, 256, 256, 256);
    prep_w<<<(48 * 256 + 255) / 256, 256, 0, stream>>>(w_self3, w3ch, w3cl, 8, 256, 47, 48);
    prep_w<<<(48 * 256 + 255) / 256, 256, 0, stream>>>(w_neigh3, w3ch + 12288, w3cl + 12288,
                                                       8, 256, 47, 48);

    int gemmGrid = (N + 127) / 128;

    // layer 1: 128 -> 256, relu.  H = relu(x@Ws1 + P@Wn1 + b1)
    agg128<<<(N + 7) / 8, 256, 0, stream>>>(x, csr, offs, P, N);
    gemm_mfma<16><<<gemmGrid, 256, 0, stream>>>(x, P, w1sh, w1sl, w1nh, w1nl, b1, H, nullptr,
                                                N, 128, 256, 1, 2, 0);
    // layer 2: 256 -> 256, relu.  H = relu(H@Ws2 + P@Wn2 + b2)  (in place)
    agg256<<<(N + 3) / 4, 256, 0, stream>>>(H, csr, offs, P, N);
    gemm_mfma<16><<<gemmGrid, 256, 0, stream>>>(H, P, w2sh, w2sl, w2nh, w2nl, b2, H, nullptr,
                                                N, 256, 256, 1, 2, 0);
    // layer 3: transform-then-aggregate.  S = H@Ws3+b3, Y = H@Wn3 (one dual GEMM),
    // then out = S + mean-agg(Y).
    gemm_mfma<6><<<gemmGrid, 256, 0, stream>>>(H, nullptr, w3ch, w3cl, nullptr, nullptr, b3,
                                               S, Y, N, 256, 96, 0, 1, 1);
    agg_l3<<<(N + 15) / 16, 256, 0, stream>>>(Y, S, csr, offs, out, N);
}

// Round 5
// 1036.797 us; speedup vs baseline: 2.0397x; 1.0351x over previous
//
#include <hip/hip_runtime.h>

#define N_NODES 100000
#define N_EDGES 1600000

typedef __attribute__((ext_vector_type(8))) short short8;
typedef __attribute__((ext_vector_type(8))) unsigned short ushort8;
typedef __attribute__((ext_vector_type(4))) float floatx4;

// ---------------- bf16 split helpers ----------------

__device__ __forceinline__ unsigned short f2bf(float f) {
    unsigned int u = __float_as_uint(f);
    unsigned int r = (u + 0x7FFFu + ((u >> 16) & 1u)) >> 16;  // RN-even
    return (unsigned short)r;
}
__device__ __forceinline__ float bf2f(unsigned short h) {
    return __uint_as_float(((unsigned int)h) << 16);
}
__device__ __forceinline__ void cv2(float v, unsigned short& h, unsigned short& l) {
    h = f2bf(v);
    l = f2bf(v - bf2f(h));
}

// ---------------- CSR build ----------------

__global__ void deg_kernel(const int* __restrict__ dst, int* __restrict__ deg, int e) {
    int i = blockIdx.x * blockDim.x + threadIdx.x;
    if (i < e) atomicAdd(&deg[dst[i]], 1);
}

__global__ __launch_bounds__(1024) void scan_kernel(const int* __restrict__ deg,
                                                    int* __restrict__ offs, int n) {
    __shared__ int wsum[16];
    __shared__ int carry;
    int t = threadIdx.x;
    int lane = t & 63, w = t >> 6;
    if (t == 0) carry = 0;
    __syncthreads();
    for (int start = 0; start < n; start += 1024) {
        int i = start + t;
        int v = (i < n) ? deg[i] : 0;
        int s = v;
        #pragma unroll
        for (int d = 1; d < 64; d <<= 1) {
            int u = __shfl_up(s, d, 64);
            if (lane >= d) s += u;
        }
        if (lane == 63) wsum[w] = s;
        __syncthreads();
        int wbase = 0;
        for (int j = 0; j < w; ++j) wbase += wsum[j];
        int base = carry;
        if (i < n) offs[i] = base + wbase + s - v;
        __syncthreads();
        if (t == 1023) carry = base + wbase + s;
        __syncthreads();
    }
    if (t == 0) offs[n] = carry;
}

__global__ void fill_csr(const int* __restrict__ src, const int* __restrict__ dst,
                         const int* __restrict__ offs, int* __restrict__ cursor,
                         int* __restrict__ csr, int e) {
    int i = blockIdx.x * blockDim.x + threadIdx.x;
    if (i < e) {
        int d = dst[i];
        int pos = offs[d] + atomicAdd(&cursor[d], 1);
        csr[pos] = src[i];
    }
}

// ---------------- x -> bf16 convert (vectorized) ----------------

__global__ void cvt_bf16(const float4* __restrict__ in, ushort4* __restrict__ out, int n4) {
    int i = blockIdx.x * blockDim.x + threadIdx.x;
    if (i < n4) {
        float4 v = in[i];
        ushort4 o;
        o.x = f2bf(v.x); o.y = f2bf(v.y); o.z = f2bf(v.z); o.w = f2bf(v.w);
        out[i] = o;
    }
}

// ---------------- mean aggregation (bf16 gather, fp32 accumulate) ----------------
// Simple sequential-index loop (round-3 form): compiler software-pipelines it.

// D=256: one wave per node, ushort4 (4 bf16) per lane.
__global__ __launch_bounds__(256) void agg256b(const unsigned short* __restrict__ Hh,
                                               const int* __restrict__ csr,
                                               const int* __restrict__ offs,
                                               float* __restrict__ agg, int n) {
    int node = blockIdx.x * 4 + (threadIdx.x >> 6);
    int lane = threadIdx.x & 63;
    if (node >= n) return;
    int e0 = offs[node], e1 = offs[node + 1];
    float a0 = 0.f, a1 = 0.f, a2 = 0.f, a3 = 0.f;
    for (int e = e0; e < e1; ++e) {
        int s = csr[e];
        ushort4 u = ((const ushort4*)(Hh + (size_t)s * 256))[lane];
        a0 += bf2f(u.x); a1 += bf2f(u.y); a2 += bf2f(u.z); a3 += bf2f(u.w);
    }
    float inv = 1.0f / fmaxf((float)(e1 - e0), 1.0f);
    float4 r = {a0 * inv, a1 * inv, a2 * inv, a3 * inv};
    ((float4*)(agg + (size_t)node * 256))[lane] = r;
}

// D=128: 32-lane group per node, ushort4 per lane.
__global__ __launch_bounds__(256) void agg128b(const unsigned short* __restrict__ xb,
                                               const int* __restrict__ csr,
                                               const int* __restrict__ offs,
                                               float* __restrict__ agg, int n) {
    int node = blockIdx.x * 8 + (threadIdx.x >> 5);
    int sl = threadIdx.x & 31;
    if (node >= n) return;
    int e0 = offs[node], e1 = offs[node + 1];
    float a0 = 0.f, a1 = 0.f, a2 = 0.f, a3 = 0.f;
    for (int e = e0; e < e1; ++e) {
        int s = csr[e];
        ushort4 u = ((const ushort4*)(xb + (size_t)s * 128))[sl];
        a0 += bf2f(u.x); a1 += bf2f(u.y); a2 += bf2f(u.z); a3 += bf2f(u.w);
    }
    float inv = 1.0f / fmaxf((float)(e1 - e0), 1.0f);
    float4 r = {a0 * inv, a1 * inv, a2 * inv, a3 * inv};
    ((float4*)(agg + (size_t)node * 128))[sl] = r;
}

// Layer-3 finish: out[node][0:47] = S[node] + mean(Y[nbrs]); fp32 gather (error-critical).
__global__ __launch_bounds__(256) void agg_l3(const float* __restrict__ Y,
                                              const float* __restrict__ S,
                                              const int* __restrict__ csr,
                                              const int* __restrict__ offs,
                                              float* __restrict__ out, int n) {
    int node = blockIdx.x * 16 + (threadIdx.x >> 4);
    int sl = threadIdx.x & 15;
    if (node >= n) return;
    int c = sl < 12 ? sl : 11;
    int e0 = offs[node], e1 = offs[node + 1];
    float4 acc = {0.f, 0.f, 0.f, 0.f};
    for (int e = e0; e < e1; ++e) {
        int s = csr[e];
        float4 f = ((const float4*)(Y + (size_t)s * 48))[c];
        acc.x += f.x; acc.y += f.y; acc.z += f.z; acc.w += f.w;
    }
    float inv = 1.0f / fmaxf((float)(e1 - e0), 1.0f);
    float4 sv = ((const float4*)(S + (size_t)node * 48))[c];
    float r[4] = {sv.x + acc.x * inv, sv.y + acc.y * inv, sv.z + acc.z * inv,
                  sv.w + acc.w * inv};
    if (sl < 12) {
        #pragma unroll
        for (int k = 0; k < 4; ++k) {
            int col = c * 4 + k;
            if (col < 47) out[(size_t)node * 47 + col] = r[k];
        }
    }
}

// ---------------- weight prep: W[K][dout] fp32 -> Wt_hi/lo[npad][K] bf16 ----------------

__global__ void prep_w(const float* __restrict__ W, unsigned short* __restrict__ hi,
                       unsigned short* __restrict__ lo, int kshift, int K, int dout,
                       int npad) {
    int i = blockIdx.x * blockDim.x + threadIdx.x;
    if (i >= npad * K) return;
    int n_idx = i >> kshift;
    int k = i & (K - 1);
    float v = (n_idx < dout) ? W[(size_t)k * dout + n_idx] : 0.f;
    unsigned short h, l;
    cv2(v, h, l);
    hi[i] = h;
    lo[i] = l;
}

// ---------------- MFMA GEMM (split-bf16, fp32-accurate) ----------------
// A1FMT: 0 = A1 fp32 (cv2 in staging); 1 = A1 pre-split (A1h,A1l).
// OUTFMT: 1 = write split bf16 (outh,outl) with bias+relu (dout=256);
//         2 = dual fp32: cols 0-47 -> S (stride 48, +bias), 48-95 -> Y (stride 48).
// phases: 2 = self+neigh; 1 = self only (layer 3 combined weight).
// In-place (layer 2): block reads only its own 128-row stripe of A1h/A1l and
// writes the same stripe in the epilogue -> safe.

template <int NTILES, int A1FMT, int OUTFMT>
__global__ __launch_bounds__(256, 2) void gemm_mfma(
    const float* __restrict__ A1f, const unsigned short* __restrict__ A1h,
    const unsigned short* __restrict__ A1l, const float* __restrict__ A2,
    const unsigned short* __restrict__ W1h, const unsigned short* __restrict__ W1l,
    const unsigned short* __restrict__ W2h, const unsigned short* __restrict__ W2l,
    const float* __restrict__ bias, float* __restrict__ outS, float* __restrict__ outY,
    unsigned short* __restrict__ outh, unsigned short* __restrict__ outl, int n, int K,
    int dout, int relu, int phases) {
    constexpr int NPAD = NTILES * 16;
    constexpr int LDT = 40;
    __shared__ unsigned short As_h[128 * LDT];
    __shared__ unsigned short As_l[128 * LDT];
    __shared__ unsigned short Bs_h[NPAD * LDT];
    __shared__ unsigned short Bs_l[NPAD * LDT];

    const int t = threadIdx.x;
    const int bm = blockIdx.x * 128;
    const int lane = t & 63;
    const int w = t >> 6;
    const int quad = lane >> 4;
    const int tl = lane & 15;
    const int mw = w * 32;

    floatx4 acc[2][NTILES];
    #pragma unroll
    for (int i = 0; i < 2; ++i)
        #pragma unroll
        for (int j = 0; j < NTILES; ++j) acc[i][j] = (floatx4){0.f, 0.f, 0.f, 0.f};

    const int arow = t >> 1;
    const int acol = (t & 1) << 4;

    for (int phase = 0; phase < phases; ++phase) {
        const unsigned short* __restrict__ Wh = phase ? W2h : W1h;
        const unsigned short* __restrict__ Wl = phase ? W2l : W1l;
        for (int k0 = 0; k0 < K; k0 += 32) {
            __syncthreads();
            // ---- stage A ----
            if (A1FMT == 1 && phase == 0) {
                ushort8 h0 = {0}, h1 = {0}, l0 = {0}, l1 = {0};
                if (bm + arow < n) {
                    const ushort8* hp =
                        (const ushort8*)(A1h + (size_t)(bm + arow) * K + k0 + acol);
                    const ushort8* lp =
                        (const ushort8*)(A1l + (size_t)(bm + arow) * K + k0 + acol);
                    h0 = hp[0]; h1 = hp[1];
                    l0 = lp[0]; l1 = lp[1];
                }
                *(ushort8*)&As_h[arow * LDT + acol] = h0;
                *(ushort8*)&As_h[arow * LDT + acol + 8] = h1;
                *(ushort8*)&As_l[arow * LDT + acol] = l0;
                *(ushort8*)&As_l[arow * LDT + acol + 8] = l1;
            } else {
                const float* __restrict__ A = phase ? A2 : A1f;
                float f[16];
                if (bm + arow < n) {
                    const float4* ap =
                        (const float4*)(A + (size_t)(bm + arow) * K + k0 + acol);
                    float4 v0 = ap[0], v1 = ap[1], v2 = ap[2], v3 = ap[3];
                    f[0] = v0.x; f[1] = v0.y; f[2] = v0.z; f[3] = v0.w;
                    f[4] = v1.x; f[5] = v1.y; f[6] = v1.z; f[7] = v1.w;
                    f[8] = v2.x; f[9] = v2.y; f[10] = v2.z; f[11] = v2.w;
                    f[12] = v3.x; f[13] = v3.y; f[14] = v3.z; f[15] = v3.w;
                } else {
                    #pragma unroll
                    for (int j = 0; j < 16; ++j) f[j] = 0.f;
                }
                ushort8 h0, l0, h1, l1;
                #pragma unroll
                for (int j = 0; j < 8; ++j) {
                    unsigned short hh, ll;
                    cv2(f[j], hh, ll);
                    h0[j] = hh; l0[j] = ll;
                    cv2(f[8 + j], hh, ll);
                    h1[j] = hh; l1[j] = ll;
                }
                *(ushort8*)&As_h[arow * LDT + acol] = h0;
                *(ushort8*)&As_h[arow * LDT + acol + 8] = h1;
                *(ushort8*)&As_l[arow * LDT + acol] = l0;
                *(ushort8*)&As_l[arow * LDT + acol + 8] = l1;
            }
            // ---- stage B ----
            if (t < NPAD) {
                const ushort8* sh = (const ushort8*)(Wh + (size_t)t * K + k0);
                const ushort8* sl2 = (const ushort8*)(Wl + (size_t)t * K + k0);
                ushort8 b0 = sh[0], b1 = sh[1], b2 = sh[2], b3 = sh[3];
                ushort8 c0 = sl2[0], c1 = sl2[1], c2 = sl2[2], c3 = sl2[3];
                *(ushort8*)&Bs_h[t * LDT + 0] = b0;
                *(ushort8*)&Bs_h[t * LDT + 8] = b1;
                *(ushort8*)&Bs_h[t * LDT + 16] = b2;
                *(ushort8*)&Bs_h[t * LDT + 24] = b3;
                *(ushort8*)&Bs_l[t * LDT + 0] = c0;
                *(ushort8*)&Bs_l[t * LDT + 8] = c1;
                *(ushort8*)&Bs_l[t * LDT + 16] = c2;
                *(ushort8*)&Bs_l[t * LDT + 24] = c3;
            }
            __syncthreads();
            // ---- compute ----
            short8 ah0 = *(const short8*)&As_h[(mw + tl) * LDT + quad * 8];
            short8 ah1 = *(const short8*)&As_h[(mw + 16 + tl) * LDT + quad * 8];
            short8 al0 = *(const short8*)&As_l[(mw + tl) * LDT + quad * 8];
            short8 al1 = *(const short8*)&As_l[(mw + 16 + tl) * LDT + quad * 8];
            #pragma unroll
            for (int nt = 0; nt < NTILES; ++nt) {
                short8 bh = *(const short8*)&Bs_h[(nt * 16 + tl) * LDT + quad * 8];
                short8 bl = *(const short8*)&Bs_l[(nt * 16 + tl) * LDT + quad * 8];
                acc[0][nt] = __builtin_amdgcn_mfma_f32_16x16x32_bf16(ah0, bh, acc[0][nt], 0, 0, 0);
                acc[1][nt] = __builtin_amdgcn_mfma_f32_16x16x32_bf16(ah1, bh, acc[1][nt], 0, 0, 0);
                acc[0][nt] = __builtin_amdgcn_mfma_f32_16x16x32_bf16(al0, bh, acc[0][nt], 0, 0, 0);
                acc[1][nt] = __builtin_amdgcn_mfma_f32_16x16x32_bf16(al1, bh, acc[1][nt], 0, 0, 0);
                acc[0][nt] = __builtin_amdgcn_mfma_f32_16x16x32_bf16(ah0, bl, acc[0][nt], 0, 0, 0);
                acc[1][nt] = __builtin_amdgcn_mfma_f32_16x16x32_bf16(ah1, bl, acc[1][nt], 0, 0, 0);
            }
        }
    }
    // ---- epilogue ----
    #pragma unroll
    for (int mt = 0; mt < 2; ++mt) {
        #pragma unroll
        for (int nt = 0; nt < NTILES; ++nt) {
            int gc = nt * 16 + tl;
            if (OUTFMT == 1 && gc >= dout) continue;
            #pragma unroll
            for (int r = 0; r < 4; ++r) {
                int gr = bm + mw + mt * 16 + quad * 4 + r;
                if (gr >= n) continue;
                float v = acc[mt][nt][r];
                if (OUTFMT == 1) {
                    v += bias[gc];
                    if (relu) v = fmaxf(v, 0.f);
                    unsigned short hh, ll;
                    cv2(v, hh, ll);
                    outh[(size_t)gr * 256 + gc] = hh;
                    outl[(size_t)gr * 256 + gc] = ll;
                } else {  // OUTFMT == 2
                    if (gc < 48) {
                        v += (gc < 47) ? bias[gc] : 0.f;
                        outS[(size_t)gr * 48 + gc] = v;
                    } else {
                        outY[(size_t)gr * 48 + (gc - 48)] = v;
                    }
                }
            }
        }
    }
}

extern "C" void kernel_launch(void* const* d_in, const int* in_sizes, int n_in,
                              void* d_out, int out_size, void* d_ws, size_t ws_size,
                              hipStream_t stream) {
    (void)in_sizes; (void)n_in; (void)out_size; (void)ws_size;
    const int N = N_NODES, E = N_EDGES;
    const float* x = (const float*)d_in[0];
    const int* src = (const int*)d_in[1];
    const int* dst = (const int*)d_in[2];
    const float* w_self1 = (const float*)d_in[3];
    const float* w_neigh1 = (const float*)d_in[4];
    const float* b1 = (const float*)d_in[5];
    const float* w_self2 = (const float*)d_in[6];
    const float* w_neigh2 = (const float*)d_in[7];
    const float* b2 = (const float*)d_in[8];
    const float* w_self3 = (const float*)d_in[9];
    const float* w_neigh3 = (const float*)d_in[10];
    const float* b3 = (const float*)d_in[11];
    float* out = (float*)d_out;

    // workspace layout (~213 MB, unchanged from passing round)
    float* P = (float*)d_ws;                        // N*256 fp32 (agg out; S/Y for L3)
    unsigned short* Hh = (unsigned short*)(P + (size_t)N * 256);  // N*256 bf16 hi
    unsigned short* Hl = Hh + (size_t)N * 256;                    // N*256 bf16 lo
    int* deg = (int*)(Hl + (size_t)N * 256);        // N (reused as cursor)
    int* offs = deg + N;                            // N+4
    int* csr = offs + N + 4;                        // E
    unsigned short* wq = (unsigned short*)(csr + E);
    unsigned short* w1sh = wq;                      // 256*128 each
    unsigned short* w1sl = w1sh + 32768;
    unsigned short* w1nh = w1sl + 32768;
    unsigned short* w1nl = w1nh + 32768;
    unsigned short* w2sh = w1nl + 32768;            // 256*256 each
    unsigned short* w2sl = w2sh + 65536;
    unsigned short* w2nh = w2sl + 65536;
    unsigned short* w2nl = w2nh + 65536;
    unsigned short* w3ch = w2nl + 65536;            // combined [96][256] hi
    unsigned short* w3cl = w3ch + 24576;            // combined lo
    // overlays on P:
    unsigned short* xb = (unsigned short*)(P + (size_t)N * 128);  // N*128 bf16 (layer 1)
    float* S = P;                                   // N*48 (layer 3)
    float* Y = P + (size_t)N * 48;                  // N*48

    hipMemsetAsync(deg, 0, N * sizeof(int), stream);
    deg_kernel<<<(E + 255) / 256, 256, 0, stream>>>(dst, deg, E);
    scan_kernel<<<1, 1024, 0, stream>>>(deg, offs, N);
    hipMemsetAsync(deg, 0, N * sizeof(int), stream);
    fill_csr<<<(E + 255) / 256, 256, 0, stream>>>(src, dst, offs, deg, csr, E);

    prep_w<<<(256 * 128 + 255) / 256, 256, 0, stream>>>(w_self1, w1sh, w1sl, 7, 128, 256, 256);
    prep_w<<<(256 * 128 + 255) / 256, 256, 0, stream>>>(w_neigh1, w1nh, w1nl, 7, 128, 256, 256);
    prep_w<<<(256 * 256 + 255) / 256, 256, 0, stream>>>(w_self2, w2sh, w2sl, 8, 256, 256, 256);
    prep_w<<<(256 * 256 + 255) / 256, 256, 0, stream>>>(w_neigh2, w2nh, w2nl, 8, 256, 256, 256);
    prep_w<<<(48 * 256 + 255) / 256, 256, 0, stream>>>(w_self3, w3ch, w3cl, 8, 256, 47, 48);
    prep_w<<<(48 * 256 + 255) / 256, 256, 0, stream>>>(w_neigh3, w3ch + 12288, w3cl + 12288,
                                                       8, 256, 47, 48);

    int gemmGrid = (N + 127) / 128;

    // layer 1: 128 -> 256, relu.  Hh/Hl = split(relu(x@Ws1 + P@Wn1 + b1))
    cvt_bf16<<<(N * 128 / 4 + 255) / 256, 256, 0, stream>>>((const float4*)x, (ushort4*)xb,
                                                            N * 128 / 4);
    agg128b<<<(N + 7) / 8, 256, 0, stream>>>(xb, csr, offs, P, N);
    gemm_mfma<16, 0, 1><<<gemmGrid, 256, 0, stream>>>(x, nullptr, nullptr, P, w1sh, w1sl,
                                                      w1nh, w1nl, b1, nullptr, nullptr, Hh,
                                                      Hl, N, 128, 256, 1, 2);
    // layer 2: 256 -> 256, relu.  Hh/Hl = split(relu((Hh+Hl)@Ws2 + P@Wn2 + b2)) in place
    agg256b<<<(N + 3) / 4, 256, 0, stream>>>(Hh, csr, offs, P, N);
    gemm_mfma<16, 1, 1><<<gemmGrid, 256, 0, stream>>>(nullptr, Hh, Hl, P, w2sh, w2sl, w2nh,
                                                      w2nl, b2, nullptr, nullptr, Hh, Hl, N,
                                                      256, 256, 1, 2);
    // layer 3: S = H@Ws3+b3, Y = H@Wn3 (dual GEMM), then out = S + mean-agg(Y)
    gemm_mfma<6, 1, 2><<<gemmGrid, 256, 0, stream>>>(nullptr, Hh, Hl, nullptr, w3ch, w3cl,
                                                     nullptr, nullptr, b3, S, Y, nullptr,
                                                     nullptr, N, 256, 96, 0, 1);
    agg_l3<<<(N + 15) / 16, 256, 0, stream>>>(Y, S, csr, offs, out, N);
}

// Round 6
// 974.598 us; speedup vs baseline: 2.1699x; 1.0638x over previous
//
#include <hip/hip_runtime.h>

#define N_NODES 100000
#define N_EDGES 1600000

typedef __attribute__((ext_vector_type(8))) _Float16 half8;
typedef __attribute__((ext_vector_type(4))) _Float16 half4v;
typedef __attribute__((ext_vector_type(4))) float floatx4;

// ---------------- CSR build ----------------

__global__ void deg_kernel(const int* __restrict__ dst, int* __restrict__ deg, int e) {
    int i = blockIdx.x * blockDim.x + threadIdx.x;
    if (i < e) atomicAdd(&deg[dst[i]], 1);
}

__global__ __launch_bounds__(1024) void scan_kernel(const int* __restrict__ deg,
                                                    int* __restrict__ offs, int n) {
    __shared__ int wsum[16];
    __shared__ int carry;
    int t = threadIdx.x;
    int lane = t & 63, w = t >> 6;
    if (t == 0) carry = 0;
    __syncthreads();
    for (int start = 0; start < n; start += 1024) {
        int i = start + t;
        int v = (i < n) ? deg[i] : 0;
        int s = v;
        #pragma unroll
        for (int d = 1; d < 64; d <<= 1) {
            int u = __shfl_up(s, d, 64);
            if (lane >= d) s += u;
        }
        if (lane == 63) wsum[w] = s;
        __syncthreads();
        int wbase = 0;
        for (int j = 0; j < w; ++j) wbase += wsum[j];
        int base = carry;
        if (i < n) offs[i] = base + wbase + s - v;
        __syncthreads();
        if (t == 1023) carry = base + wbase + s;
        __syncthreads();
    }
    if (t == 0) offs[n] = carry;
}

__global__ void fill_csr(const int* __restrict__ src, const int* __restrict__ dst,
                         const int* __restrict__ offs, int* __restrict__ cursor,
                         int* __restrict__ csr, int e) {
    int i = blockIdx.x * blockDim.x + threadIdx.x;
    if (i < e) {
        int d = dst[i];
        int pos = offs[d] + atomicAdd(&cursor[d], 1);
        csr[pos] = src[i];
    }
}

// ---------------- x -> fp16 hi/lo split ----------------

__global__ void split_f16(const float4* __restrict__ in, half4v* __restrict__ oh,
                          half4v* __restrict__ ol, int n4) {
    int i = blockIdx.x * blockDim.x + threadIdx.x;
    if (i >= n4) return;
    float4 v = in[i];
    half4v h, l;
    h[0] = (_Float16)v.x; l[0] = (_Float16)(v.x - (float)h[0]);
    h[1] = (_Float16)v.y; l[1] = (_Float16)(v.y - (float)h[1]);
    h[2] = (_Float16)v.z; l[2] = (_Float16)(v.z - (float)h[2]);
    h[3] = (_Float16)v.w; l[3] = (_Float16)(v.w - (float)h[3]);
    oh[i] = h;
    ol[i] = l;
}

// ---------------- mean aggregation (fp16 gather, fp32 accumulate, split-fp16 out) ----

__global__ __launch_bounds__(256) void agg256h(const _Float16* __restrict__ Hh,
                                               const int* __restrict__ csr,
                                               const int* __restrict__ offs,
                                               _Float16* __restrict__ Ph,
                                               _Float16* __restrict__ Pl, int n) {
    int node = blockIdx.x * 4 + (threadIdx.x >> 6);
    int lane = threadIdx.x & 63;
    if (node >= n) return;
    int e0 = offs[node], e1 = offs[node + 1];
    float a0 = 0.f, a1 = 0.f, a2 = 0.f, a3 = 0.f;
    for (int e = e0; e < e1; ++e) {
        int s = csr[e];
        half4v u = ((const half4v*)(Hh + (size_t)s * 256))[lane];
        a0 += (float)u[0]; a1 += (float)u[1]; a2 += (float)u[2]; a3 += (float)u[3];
    }
    float inv = 1.0f / fmaxf((float)(e1 - e0), 1.0f);
    a0 *= inv; a1 *= inv; a2 *= inv; a3 *= inv;
    half4v rh, rl;
    rh[0] = (_Float16)a0; rl[0] = (_Float16)(a0 - (float)rh[0]);
    rh[1] = (_Float16)a1; rl[1] = (_Float16)(a1 - (float)rh[1]);
    rh[2] = (_Float16)a2; rl[2] = (_Float16)(a2 - (float)rh[2]);
    rh[3] = (_Float16)a3; rl[3] = (_Float16)(a3 - (float)rh[3]);
    ((half4v*)(Ph + (size_t)node * 256))[lane] = rh;
    ((half4v*)(Pl + (size_t)node * 256))[lane] = rl;
}

__global__ __launch_bounds__(256) void agg128h(const _Float16* __restrict__ xh,
                                               const int* __restrict__ csr,
                                               const int* __restrict__ offs,
                                               _Float16* __restrict__ Ph,
                                               _Float16* __restrict__ Pl, int n) {
    int node = blockIdx.x * 8 + (threadIdx.x >> 5);
    int sl = threadIdx.x & 31;
    if (node >= n) return;
    int e0 = offs[node], e1 = offs[node + 1];
    float a0 = 0.f, a1 = 0.f, a2 = 0.f, a3 = 0.f;
    for (int e = e0; e < e1; ++e) {
        int s = csr[e];
        half4v u = ((const half4v*)(xh + (size_t)s * 128))[sl];
        a0 += (float)u[0]; a1 += (float)u[1]; a2 += (float)u[2]; a3 += (float)u[3];
    }
    float inv = 1.0f / fmaxf((float)(e1 - e0), 1.0f);
    a0 *= inv; a1 *= inv; a2 *= inv; a3 *= inv;
    half4v rh, rl;
    rh[0] = (_Float16)a0; rl[0] = (_Float16)(a0 - (float)rh[0]);
    rh[1] = (_Float16)a1; rl[1] = (_Float16)(a1 - (float)rh[1]);
    rh[2] = (_Float16)a2; rl[2] = (_Float16)(a2 - (float)rh[2]);
    rh[3] = (_Float16)a3; rl[3] = (_Float16)(a3 - (float)rh[3]);
    ((half4v*)(Ph + (size_t)node * 128))[sl] = rh;
    ((half4v*)(Pl + (size_t)node * 128))[sl] = rl;
}

// Layer-3 finish: out[node][0:47] = S[node] + mean(Y[nbrs]); fp32 (error-critical).
__global__ __launch_bounds__(256) void agg_l3(const float* __restrict__ Y,
                                              const float* __restrict__ S,
                                              const int* __restrict__ csr,
                                              const int* __restrict__ offs,
                                              float* __restrict__ out, int n) {
    int node = blockIdx.x * 16 + (threadIdx.x >> 4);
    int sl = threadIdx.x & 15;
    if (node >= n) return;
    int c = sl < 12 ? sl : 11;
    int e0 = offs[node], e1 = offs[node + 1];
    float4 acc = {0.f, 0.f, 0.f, 0.f};
    for (int e = e0; e < e1; ++e) {
        int s = csr[e];
        float4 f = ((const float4*)(Y + (size_t)s * 48))[c];
        acc.x += f.x; acc.y += f.y; acc.z += f.z; acc.w += f.w;
    }
    float inv = 1.0f / fmaxf((float)(e1 - e0), 1.0f);
    float4 sv = ((const float4*)(S + (size_t)node * 48))[c];
    float r[4] = {sv.x + acc.x * inv, sv.y + acc.y * inv, sv.z + acc.z * inv,
                  sv.w + acc.w * inv};
    if (sl < 12) {
        #pragma unroll
        for (int k = 0; k < 4; ++k) {
            int col = c * 4 + k;
            if (col < 47) out[(size_t)node * 47 + col] = r[k];
        }
    }
}

// ---------------- weight prep: W[K][dout] fp32 -> Wt[npad][K] fp16 ----------------

__global__ void prep_w(const float* __restrict__ W, _Float16* __restrict__ hi, int kshift,
                       int K, int dout, int npad) {
    int i = blockIdx.x * blockDim.x + threadIdx.x;
    if (i >= npad * K) return;
    int n_idx = i >> kshift;
    int k = i & (K - 1);
    float v = (n_idx < dout) ? W[(size_t)k * dout + n_idx] : 0.f;
    hi[i] = (_Float16)v;
}

// ---------------- MFMA GEMM (fp16 2-product split, A direct-from-global) -------------
// out[128 x dout] = (A1h+A1l)@W1 (+ (A2h+A2l)@W2) + b (+relu).
// C = Ah*Bh + Al*Bh : A at 2^-21, B at 2^-11 relative precision.
// Each wave owns rows [bm+w*32, bm+w*32+32): A frags are direct 16B global loads of
// its own rows -> no A staging, in-place layer 2 safe (reads precede epilogue writes
// within the wave). B staged in LDS (fp16, LDT=36: even 8/bank, conflict-free) with
// register prefetch of step s+1 issued after the barrier (latency hidden by MFMA).
// OUTFMT 1: split-fp16 H write (dout=256). OUTFMT 2: cols 0-47 -> S(+bias), 48-95 -> Y.

template <int NTILES, int OUTFMT>
__global__ __launch_bounds__(256, 2) void gemm_mfma(
    const _Float16* __restrict__ A1h, const _Float16* __restrict__ A1l,
    const _Float16* __restrict__ A2h, const _Float16* __restrict__ A2l,
    const _Float16* __restrict__ W1, const _Float16* __restrict__ W2,
    const float* __restrict__ bias, float* __restrict__ outS, float* __restrict__ outY,
    _Float16* __restrict__ outh, _Float16* __restrict__ outl, int n, int K, int dout,
    int relu, int phases) {
    constexpr int NPAD = NTILES * 16;
    constexpr int LDT = 36;
    __shared__ _Float16 Bs[NPAD * LDT];

    const int t = threadIdx.x;
    const int bm = blockIdx.x * 128;
    const int lane = t & 63;
    const int w = t >> 6;
    const int quad = lane >> 4;
    const int tl = lane & 15;
    const int r0 = bm + w * 32 + tl;
    const int r1 = r0 + 16;

    floatx4 acc[2][NTILES];
    #pragma unroll
    for (int i = 0; i < 2; ++i)
        #pragma unroll
        for (int j = 0; j < NTILES; ++j) acc[i][j] = (floatx4){0.f, 0.f, 0.f, 0.f};

    const int spp = K >> 5;  // K-steps per phase
    const int nsteps = phases * spp;

    half8 pb0, pb1, pb2, pb3;                 // B prefetch regs
    half8 pah0 = {0}, pah1 = {0}, pal0 = {0}, pal1 = {0};  // A prefetch regs

    // prologue: load step 0
    if (t < NPAD) {
        const half8* p = (const half8*)(W1 + (size_t)t * K);
        pb0 = p[0]; pb1 = p[1]; pb2 = p[2]; pb3 = p[3];
    }
    {
        int kq = quad * 8;
        if (r0 < n) {
            pah0 = *(const half8*)(A1h + (size_t)r0 * K + kq);
            pal0 = *(const half8*)(A1l + (size_t)r0 * K + kq);
        }
        if (r1 < n) {
            pah1 = *(const half8*)(A1h + (size_t)r1 * K + kq);
            pal1 = *(const half8*)(A1l + (size_t)r1 * K + kq);
        }
    }

    for (int s = 0; s < nsteps; ++s) {
        __syncthreads();  // previous step's Bs readers done
        if (t < NPAD) {
            *(half8*)&Bs[t * LDT + 0]  = pb0;
            *(half8*)&Bs[t * LDT + 8]  = pb1;
            *(half8*)&Bs[t * LDT + 16] = pb2;
            *(half8*)&Bs[t * LDT + 24] = pb3;
        }
        __syncthreads();  // Bs ready
        half8 ah0 = pah0, ah1 = pah1, al0 = pal0, al1 = pal1;
        // prefetch step s+1 (in flight across this step's MFMA)
        if (s + 1 < nsteps) {
            int s2 = s + 1;
            int ph2 = (s2 >= spp) ? 1 : 0;
            int k02 = (ph2 ? s2 - spp : s2) << 5;
            if (t < NPAD) {
                const _Float16* W = ph2 ? W2 : W1;
                const half8* p = (const half8*)(W + (size_t)t * K + k02);
                pb0 = p[0]; pb1 = p[1]; pb2 = p[2]; pb3 = p[3];
            }
            const _Float16* Ah = ph2 ? A2h : A1h;
            const _Float16* Al = ph2 ? A2l : A1l;
            int kq = k02 + quad * 8;
            pah0 = (half8){0}; pah1 = (half8){0}; pal0 = (half8){0}; pal1 = (half8){0};
            if (r0 < n) {
                pah0 = *(const half8*)(Ah + (size_t)r0 * K + kq);
                pal0 = *(const half8*)(Al + (size_t)r0 * K + kq);
            }
            if (r1 < n) {
                pah1 = *(const half8*)(Ah + (size_t)r1 * K + kq);
                pal1 = *(const half8*)(Al + (size_t)r1 * K + kq);
            }
        }
        #pragma unroll
        for (int nt = 0; nt < NTILES; ++nt) {
            half8 bh = *(const half8*)&Bs[(nt * 16 + tl) * LDT + quad * 8];
            acc[0][nt] = __builtin_amdgcn_mfma_f32_16x16x32_f16(ah0, bh, acc[0][nt], 0, 0, 0);
            acc[1][nt] = __builtin_amdgcn_mfma_f32_16x16x32_f16(ah1, bh, acc[1][nt], 0, 0, 0);
            acc[0][nt] = __builtin_amdgcn_mfma_f32_16x16x32_f16(al0, bh, acc[0][nt], 0, 0, 0);
            acc[1][nt] = __builtin_amdgcn_mfma_f32_16x16x32_f16(al1, bh, acc[1][nt], 0, 0, 0);
        }
    }

    // ---- epilogue ----
    #pragma unroll
    for (int mt = 0; mt < 2; ++mt) {
        #pragma unroll
        for (int nt = 0; nt < NTILES; ++nt) {
            int gc = nt * 16 + tl;
            if (OUTFMT == 1 && gc >= dout) continue;
            #pragma unroll
            for (int r = 0; r < 4; ++r) {
                int gr = bm + w * 32 + mt * 16 + quad * 4 + r;
                if (gr >= n) continue;
                float v = acc[mt][nt][r];
                if (OUTFMT == 1) {
                    v += bias[gc];
                    if (relu) v = fmaxf(v, 0.f);
                    _Float16 hh = (_Float16)v;
                    _Float16 ll = (_Float16)(v - (float)hh);
                    outh[(size_t)gr * 256 + gc] = hh;
                    outl[(size_t)gr * 256 + gc] = ll;
                } else {
                    if (gc < 48) {
                        v += (gc < 47) ? bias[gc] : 0.f;
                        outS[(size_t)gr * 48 + gc] = v;
                    } else {
                        outY[(size_t)gr * 48 + (gc - 48)] = v;
                    }
                }
            }
        }
    }
}

extern "C" void kernel_launch(void* const* d_in, const int* in_sizes, int n_in,
                              void* d_out, int out_size, void* d_ws, size_t ws_size,
                              hipStream_t stream) {
    (void)in_sizes; (void)n_in; (void)out_size; (void)ws_size;
    const int N = N_NODES, E = N_EDGES;
    const float* x = (const float*)d_in[0];
    const int* src = (const int*)d_in[1];
    const int* dst = (const int*)d_in[2];
    const float* w_self1 = (const float*)d_in[3];
    const float* w_neigh1 = (const float*)d_in[4];
    const float* b1 = (const float*)d_in[5];
    const float* w_self2 = (const float*)d_in[6];
    const float* w_neigh2 = (const float*)d_in[7];
    const float* b2 = (const float*)d_in[8];
    const float* w_self3 = (const float*)d_in[9];
    const float* w_neigh3 = (const float*)d_in[10];
    const float* b3 = (const float*)d_in[11];
    float* out = (float*)d_out;

    // workspace layout (~213 MB, same budget as passing rounds)
    _Float16* Ph = (_Float16*)d_ws;             // N*256 fp16 (agg hi; N*128 in L1)
    _Float16* Pl = Ph + (size_t)N * 256;        // N*256 fp16 (agg lo)
    _Float16* Hh = Pl + (size_t)N * 256;        // N*256 fp16 (hidden hi)
    _Float16* Hl = Hh + (size_t)N * 256;        // N*256 fp16 (hidden lo)
    int* deg = (int*)(Hl + (size_t)N * 256);    // N (reused as cursor)
    int* offs = deg + N;                        // N+4
    int* csr = offs + N + 4;                    // E
    _Float16* wbuf = (_Float16*)(csr + E);
    _Float16* w1s = wbuf;                       // 256*128
    _Float16* w1n = w1s + 32768;                // 256*128
    _Float16* w2s = w1n + 32768;                // 256*256
    _Float16* w2n = w2s + 65536;                // 256*256
    _Float16* w3c = w2n + 65536;                // 96*256 combined [self|neigh]
    // overlays:
    _Float16* xh = Ph + (size_t)N * 128;        // N*128 (upper half of Ph region)
    _Float16* xl = Pl + (size_t)N * 128;        // N*128 (upper half of Pl region)
    float* S = (float*)d_ws;                    // N*48 fp32 (L3, after P is dead)
    float* Y = S + (size_t)N * 48;              // N*48 fp32

    hipMemsetAsync(deg, 0, N * sizeof(int), stream);
    deg_kernel<<<(E + 255) / 256, 256, 0, stream>>>(dst, deg, E);
    scan_kernel<<<1, 1024, 0, stream>>>(deg, offs, N);
    hipMemsetAsync(deg, 0, N * sizeof(int), stream);
    fill_csr<<<(E + 255) / 256, 256, 0, stream>>>(src, dst, offs, deg, csr, E);

    split_f16<<<(N * 128 / 4 + 255) / 256, 256, 0, stream>>>((const float4*)x, (half4v*)xh,
                                                             (half4v*)xl, N * 128 / 4);
    prep_w<<<(256 * 128 + 255) / 256, 256, 0, stream>>>(w_self1, w1s, 7, 128, 256, 256);
    prep_w<<<(256 * 128 + 255) / 256, 256, 0, stream>>>(w_neigh1, w1n, 7, 128, 256, 256);
    prep_w<<<(256 * 256 + 255) / 256, 256, 0, stream>>>(w_self2, w2s, 8, 256, 256, 256);
    prep_w<<<(256 * 256 + 255) / 256, 256, 0, stream>>>(w_neigh2, w2n, 8, 256, 256, 256);
    prep_w<<<(48 * 256 + 255) / 256, 256, 0, stream>>>(w_self3, w3c, 8, 256, 47, 48);
    prep_w<<<(48 * 256 + 255) / 256, 256, 0, stream>>>(w_neigh3, w3c + 12288, 8, 256, 47, 48);

    int gemmGrid = (N + 127) / 128;

    // layer 1: 128 -> 256, relu.  Hh/Hl = split(relu(x@Ws1 + P@Wn1 + b1))
    agg128h<<<(N + 7) / 8, 256, 0, stream>>>(xh, csr, offs, Ph, Pl, N);
    gemm_mfma<16, 1><<<gemmGrid, 256, 0, stream>>>(xh, xl, Ph, Pl, w1s, w1n, b1, nullptr,
                                                   nullptr, Hh, Hl, N, 128, 256, 1, 2);
    // layer 2: 256 -> 256, relu.  Hh/Hl = split(relu(H@Ws2 + P@Wn2 + b2))  (in place)
    agg256h<<<(N + 3) / 4, 256, 0, stream>>>(Hh, csr, offs, Ph, Pl, N);
    gemm_mfma<16, 1><<<gemmGrid, 256, 0, stream>>>(Hh, Hl, Ph, Pl, w2s, w2n, b2, nullptr,
                                                   nullptr, Hh, Hl, N, 256, 256, 1, 2);
    // layer 3: S = H@Ws3+b3, Y = H@Wn3 (dual GEMM), then out = S + mean-agg(Y)
    gemm_mfma<6, 2><<<gemmGrid, 256, 0, stream>>>(Hh, Hl, nullptr, nullptr, w3c, nullptr, b3,
                                                  S, Y, nullptr, nullptr, N, 256, 96, 0, 1);
    agg_l3<<<(N + 15) / 16, 256, 0, stream>>>(Y, S, csr, offs, out, N);
}

// Round 7
// 908.566 us; speedup vs baseline: 2.3276x; 1.0727x over previous
//
#include <hip/hip_runtime.h>

#define N_NODES 100000
#define N_EDGES 1600000

typedef __attribute__((ext_vector_type(8))) _Float16 half8;
typedef __attribute__((ext_vector_type(4))) _Float16 half4v;
typedef __attribute__((ext_vector_type(4))) float floatx4;

// ---------------- CSR build ----------------

__global__ void deg_kernel(const int* __restrict__ dst, int* __restrict__ deg, int e) {
    int i = blockIdx.x * blockDim.x + threadIdx.x;
    if (i < e) atomicAdd(&deg[dst[i]], 1);
}

__global__ __launch_bounds__(1024) void scan_kernel(const int* __restrict__ deg,
                                                    int* __restrict__ offs, int n) {
    __shared__ int wsum[16];
    __shared__ int carry;
    int t = threadIdx.x;
    int lane = t & 63, w = t >> 6;
    if (t == 0) carry = 0;
    __syncthreads();
    for (int start = 0; start < n; start += 1024) {
        int i = start + t;
        int v = (i < n) ? deg[i] : 0;
        int s = v;
        #pragma unroll
        for (int d = 1; d < 64; d <<= 1) {
            int u = __shfl_up(s, d, 64);
            if (lane >= d) s += u;
        }
        if (lane == 63) wsum[w] = s;
        __syncthreads();
        int wbase = 0;
        for (int j = 0; j < w; ++j) wbase += wsum[j];
        int base = carry;
        if (i < n) offs[i] = base + wbase + s - v;
        __syncthreads();
        if (t == 1023) carry = base + wbase + s;
        __syncthreads();
    }
    if (t == 0) offs[n] = carry;
}

__global__ void fill_csr(const int* __restrict__ src, const int* __restrict__ dst,
                         const int* __restrict__ offs, int* __restrict__ cursor,
                         int* __restrict__ csr, int e) {
    int i = blockIdx.x * blockDim.x + threadIdx.x;
    if (i < e) {
        int d = dst[i];
        int pos = offs[d] + atomicAdd(&cursor[d], 1);
        csr[pos] = src[i];
    }
}

// ---------------- x -> fp16 convert ----------------

__global__ void cvt_f16(const float4* __restrict__ in, half4v* __restrict__ oh, int n4) {
    int i = blockIdx.x * blockDim.x + threadIdx.x;
    if (i >= n4) return;
    float4 v = in[i];
    half4v h;
    h[0] = (_Float16)v.x; h[1] = (_Float16)v.y;
    h[2] = (_Float16)v.z; h[3] = (_Float16)v.w;
    oh[i] = h;
}

// ---------------- mean aggregation (fp16 gather, fp32 accumulate, fp16 out) ----------

__global__ __launch_bounds__(256) void agg256h(const _Float16* __restrict__ Hh,
                                               const int* __restrict__ csr,
                                               const int* __restrict__ offs,
                                               _Float16* __restrict__ Ph, int n) {
    int node = blockIdx.x * 4 + (threadIdx.x >> 6);
    int lane = threadIdx.x & 63;
    if (node >= n) return;
    int e0 = offs[node], e1 = offs[node + 1];
    float a0 = 0.f, a1 = 0.f, a2 = 0.f, a3 = 0.f;
    for (int e = e0; e < e1; ++e) {
        int s = csr[e];
        half4v u = ((const half4v*)(Hh + (size_t)s * 256))[lane];
        a0 += (float)u[0]; a1 += (float)u[1]; a2 += (float)u[2]; a3 += (float)u[3];
    }
    float inv = 1.0f / fmaxf((float)(e1 - e0), 1.0f);
    half4v rh;
    rh[0] = (_Float16)(a0 * inv); rh[1] = (_Float16)(a1 * inv);
    rh[2] = (_Float16)(a2 * inv); rh[3] = (_Float16)(a3 * inv);
    ((half4v*)(Ph + (size_t)node * 256))[lane] = rh;
}

__global__ __launch_bounds__(256) void agg128h(const _Float16* __restrict__ xh,
                                               const int* __restrict__ csr,
                                               const int* __restrict__ offs,
                                               _Float16* __restrict__ Ph, int n) {
    int node = blockIdx.x * 8 + (threadIdx.x >> 5);
    int sl = threadIdx.x & 31;
    if (node >= n) return;
    int e0 = offs[node], e1 = offs[node + 1];
    float a0 = 0.f, a1 = 0.f, a2 = 0.f, a3 = 0.f;
    for (int e = e0; e < e1; ++e) {
        int s = csr[e];
        half4v u = ((const half4v*)(xh + (size_t)s * 128))[sl];
        a0 += (float)u[0]; a1 += (float)u[1]; a2 += (float)u[2]; a3 += (float)u[3];
    }
    float inv = 1.0f / fmaxf((float)(e1 - e0), 1.0f);
    half4v rh;
    rh[0] = (_Float16)(a0 * inv); rh[1] = (_Float16)(a1 * inv);
    rh[2] = (_Float16)(a2 * inv); rh[3] = (_Float16)(a3 * inv);
    ((half4v*)(Ph + (size_t)node * 128))[sl] = rh;
}

// Layer-3 finish: out[node][0:47] = S[node] + mean(Y[nbrs]); Y fp16 (96B rows), S fp32.
__global__ __launch_bounds__(256) void agg_l3(const _Float16* __restrict__ Y,
                                              const float* __restrict__ S,
                                              const int* __restrict__ csr,
                                              const int* __restrict__ offs,
                                              float* __restrict__ out, int n) {
    int node = blockIdx.x * 16 + (threadIdx.x >> 4);
    int sl = threadIdx.x & 15;
    if (node >= n) return;
    int c = sl < 12 ? sl : 11;
    int e0 = offs[node], e1 = offs[node + 1];
    float a0 = 0.f, a1 = 0.f, a2 = 0.f, a3 = 0.f;
    for (int e = e0; e < e1; ++e) {
        int s = csr[e];
        half4v f = ((const half4v*)(Y + (size_t)s * 48))[c];
        a0 += (float)f[0]; a1 += (float)f[1]; a2 += (float)f[2]; a3 += (float)f[3];
    }
    float inv = 1.0f / fmaxf((float)(e1 - e0), 1.0f);
    float4 sv = ((const float4*)(S + (size_t)node * 48))[c];
    float r[4] = {sv.x + a0 * inv, sv.y + a1 * inv, sv.z + a2 * inv, sv.w + a3 * inv};
    if (sl < 12) {
        #pragma unroll
        for (int k = 0; k < 4; ++k) {
            int col = c * 4 + k;
            if (col < 47) out[(size_t)node * 47 + col] = r[k];
        }
    }
}

// ---------------- weight prep: W[K][dout] fp32 -> Wt[npad][K] fp16 ----------------

__global__ void prep_w(const float* __restrict__ W, _Float16* __restrict__ hi, int kshift,
                       int K, int dout, int npad) {
    int i = blockIdx.x * blockDim.x + threadIdx.x;
    if (i >= npad * K) return;
    int n_idx = i >> kshift;
    int k = i & (K - 1);
    float v = (n_idx < dout) ? W[(size_t)k * dout + n_idx] : 0.f;
    hi[i] = (_Float16)v;
}

// ---------------- MFMA GEMM (plain fp16, A direct-from-global) -------------
// out[128 x dout] = A1@W1 (+ A2@W2) + b (+relu), fp32 accumulate.
// Each wave owns rows [bm+w*32, bm+w*32+32): A frags are direct 16B global loads
// (no A staging; in-place layer 2 safe). B staged in LDS (LDT=36, conflict-free)
// with register prefetch of step s+1 issued after the barrier.
// OUTFMT 1: fp16 H write (dout=256). OUTFMT 2: cols 0-47 -> S fp32 (+bias),
// cols 48-95 -> Y fp16 (stride 48).

template <int NTILES, int OUTFMT>
__global__ __launch_bounds__(256, 2) void gemm_mfma(
    const _Float16* __restrict__ A1h, const _Float16* __restrict__ A2h,
    const _Float16* __restrict__ W1, const _Float16* __restrict__ W2,
    const float* __restrict__ bias, float* __restrict__ outS, _Float16* __restrict__ outY,
    _Float16* __restrict__ outh, int n, int K, int dout, int relu, int phases) {
    constexpr int NPAD = NTILES * 16;
    constexpr int LDT = 36;
    __shared__ _Float16 Bs[NPAD * LDT];

    const int t = threadIdx.x;
    const int bm = blockIdx.x * 128;
    const int lane = t & 63;
    const int w = t >> 6;
    const int quad = lane >> 4;
    const int tl = lane & 15;
    const int r0 = bm + w * 32 + tl;
    const int r1 = r0 + 16;

    floatx4 acc[2][NTILES];
    #pragma unroll
    for (int i = 0; i < 2; ++i)
        #pragma unroll
        for (int j = 0; j < NTILES; ++j) acc[i][j] = (floatx4){0.f, 0.f, 0.f, 0.f};

    const int spp = K >> 5;
    const int nsteps = phases * spp;

    half8 pb0, pb1, pb2, pb3;
    half8 pah0 = {0}, pah1 = {0};

    if (t < NPAD) {
        const half8* p = (const half8*)(W1 + (size_t)t * K);
        pb0 = p[0]; pb1 = p[1]; pb2 = p[2]; pb3 = p[3];
    }
    {
        int kq = quad * 8;
        if (r0 < n) pah0 = *(const half8*)(A1h + (size_t)r0 * K + kq);
        if (r1 < n) pah1 = *(const half8*)(A1h + (size_t)r1 * K + kq);
    }

    for (int s = 0; s < nsteps; ++s) {
        __syncthreads();
        if (t < NPAD) {
            *(half8*)&Bs[t * LDT + 0]  = pb0;
            *(half8*)&Bs[t * LDT + 8]  = pb1;
            *(half8*)&Bs[t * LDT + 16] = pb2;
            *(half8*)&Bs[t * LDT + 24] = pb3;
        }
        __syncthreads();
        half8 ah0 = pah0, ah1 = pah1;
        if (s + 1 < nsteps) {
            int s2 = s + 1;
            int ph2 = (s2 >= spp) ? 1 : 0;
            int k02 = (ph2 ? s2 - spp : s2) << 5;
            if (t < NPAD) {
                const _Float16* W = ph2 ? W2 : W1;
                const half8* p = (const half8*)(W + (size_t)t * K + k02);
                pb0 = p[0]; pb1 = p[1]; pb2 = p[2]; pb3 = p[3];
            }
            const _Float16* Ah = ph2 ? A2h : A1h;
            int kq = k02 + quad * 8;
            pah0 = (half8){0}; pah1 = (half8){0};
            if (r0 < n) pah0 = *(const half8*)(Ah + (size_t)r0 * K + kq);
            if (r1 < n) pah1 = *(const half8*)(Ah + (size_t)r1 * K + kq);
        }
        #pragma unroll
        for (int nt = 0; nt < NTILES; ++nt) {
            half8 bh = *(const half8*)&Bs[(nt * 16 + tl) * LDT + quad * 8];
            acc[0][nt] = __builtin_amdgcn_mfma_f32_16x16x32_f16(ah0, bh, acc[0][nt], 0, 0, 0);
            acc[1][nt] = __builtin_amdgcn_mfma_f32_16x16x32_f16(ah1, bh, acc[1][nt], 0, 0, 0);
        }
    }

    #pragma unroll
    for (int mt = 0; mt < 2; ++mt) {
        #pragma unroll
        for (int nt = 0; nt < NTILES; ++nt) {
            int gc = nt * 16 + tl;
            if (OUTFMT == 1 && gc >= dout) continue;
            #pragma unroll
            for (int r = 0; r < 4; ++r) {
                int gr = bm + w * 32 + mt * 16 + quad * 4 + r;
                if (gr >= n) continue;
                float v = acc[mt][nt][r];
                if (OUTFMT == 1) {
                    v += bias[gc];
                    if (relu) v = fmaxf(v, 0.f);
                    outh[(size_t)gr * 256 + gc] = (_Float16)v;
                } else {
                    if (gc < 48) {
                        v += (gc < 47) ? bias[gc] : 0.f;
                        outS[(size_t)gr * 48 + gc] = v;
                    } else {
                        outY[(size_t)gr * 48 + (gc - 48)] = (_Float16)v;
                    }
                }
            }
        }
    }
}

extern "C" void kernel_launch(void* const* d_in, const int* in_sizes, int n_in,
                              void* d_out, int out_size, void* d_ws, size_t ws_size,
                              hipStream_t stream) {
    (void)in_sizes; (void)n_in; (void)out_size; (void)ws_size;
    const int N = N_NODES, E = N_EDGES;
    const float* x = (const float*)d_in[0];
    const int* src = (const int*)d_in[1];
    const int* dst = (const int*)d_in[2];
    const float* w_self1 = (const float*)d_in[3];
    const float* w_neigh1 = (const float*)d_in[4];
    const float* b1 = (const float*)d_in[5];
    const float* w_self2 = (const float*)d_in[6];
    const float* w_neigh2 = (const float*)d_in[7];
    const float* b2 = (const float*)d_in[8];
    const float* w_self3 = (const float*)d_in[9];
    const float* w_neigh3 = (const float*)d_in[10];
    const float* b3 = (const float*)d_in[11];
    float* out = (float*)d_out;

    // workspace layout (~110 MB)
    _Float16* Ph = (_Float16*)d_ws;             // N*256 fp16 (agg; N*128 in L1)
    _Float16* Hh = Ph + (size_t)N * 256;        // N*256 fp16 (hidden)
    int* deg = (int*)(Hh + (size_t)N * 256);    // N (reused as cursor)
    int* offs = deg + N;                        // N+4
    int* csr = offs + N + 4;                    // E
    _Float16* wbuf = (_Float16*)(csr + E);
    _Float16* w1s = wbuf;                       // 256*128
    _Float16* w1n = w1s + 32768;                // 256*128
    _Float16* w2s = w1n + 32768;                // 256*256
    _Float16* w2n = w2s + 65536;                // 256*256
    _Float16* w3c = w2n + 65536;                // 96*256 combined [self|neigh]
    // overlays on the Ph region:
    _Float16* xh = Ph + (size_t)N * 128;        // N*128 fp16 (layer 1, upper half)
    float* S = (float*)Ph;                      // N*48 fp32 (layer 3; P dead)
    _Float16* Y = (_Float16*)(S + (size_t)N * 48);  // N*48 fp16

    hipMemsetAsync(deg, 0, N * sizeof(int), stream);
    deg_kernel<<<(E + 255) / 256, 256, 0, stream>>>(dst, deg, E);
    scan_kernel<<<1, 1024, 0, stream>>>(deg, offs, N);
    hipMemsetAsync(deg, 0, N * sizeof(int), stream);
    fill_csr<<<(E + 255) / 256, 256, 0, stream>>>(src, dst, offs, deg, csr, E);

    cvt_f16<<<(N * 128 / 4 + 255) / 256, 256, 0, stream>>>((const float4*)x, (half4v*)xh,
                                                           N * 128 / 4);
    prep_w<<<(256 * 128 + 255) / 256, 256, 0, stream>>>(w_self1, w1s, 7, 128, 256, 256);
    prep_w<<<(256 * 128 + 255) / 256, 256, 0, stream>>>(w_neigh1, w1n, 7, 128, 256, 256);
    prep_w<<<(256 * 256 + 255) / 256, 256, 0, stream>>>(w_self2, w2s, 8, 256, 256, 256);
    prep_w<<<(256 * 256 + 255) / 256, 256, 0, stream>>>(w_neigh2, w2n, 8, 256, 256, 256);
    prep_w<<<(48 * 256 + 255) / 256, 256, 0, stream>>>(w_self3, w3c, 8, 256, 47, 48);
    prep_w<<<(48 * 256 + 255) / 256, 256, 0, stream>>>(w_neigh3, w3c + 12288, 8, 256, 47, 48);

    int gemmGrid = (N + 127) / 128;

    // layer 1: 128 -> 256, relu.  Hh = fp16(relu(x@Ws1 + P@Wn1 + b1))
    agg128h<<<(N + 7) / 8, 256, 0, stream>>>(xh, csr, offs, Ph, N);
    gemm_mfma<16, 1><<<gemmGrid, 256, 0, stream>>>(xh, Ph, w1s, w1n, b1, nullptr, nullptr,
                                                   Hh, N, 128, 256, 1, 2);
    // layer 2: 256 -> 256, relu.  Hh = fp16(relu(H@Ws2 + P@Wn2 + b2))  (in place)
    agg256h<<<(N + 3) / 4, 256, 0, stream>>>(Hh, csr, offs, Ph, N);
    gemm_mfma<16, 1><<<gemmGrid, 256, 0, stream>>>(Hh, Ph, w2s, w2n, b2, nullptr, nullptr,
                                                   Hh, N, 256, 256, 1, 2);
    // layer 3: S = H@Ws3+b3 (fp32), Y = H@Wn3 (fp16) in one dual GEMM, then
    // out = S + mean-agg(Y).
    gemm_mfma<6, 2><<<gemmGrid, 256, 0, stream>>>(Hh, nullptr, w3c, nullptr, b3, S, Y,
                                                  nullptr, N, 256, 96, 0, 1);
    agg_l3<<<(N + 15) / 16, 256, 0, stream>>>(Y, S, csr, offs, out, N);
}

// Round 9
// 831.944 us; speedup vs baseline: 2.5420x; 1.0921x over previous
//
#include <hip/hip_runtime.h>

#define N_NODES 100000
#define N_EDGES 1600000

typedef __attribute__((ext_vector_type(8))) _Float16 half8;
typedef __attribute__((ext_vector_type(4))) _Float16 half4v;
typedef __attribute__((ext_vector_type(4))) float floatx4;

// ---------------- CSR build ----------------

__global__ void deg_kernel(const int* __restrict__ dst, int* __restrict__ deg, int e) {
    int i = blockIdx.x * blockDim.x + threadIdx.x;
    if (i < e) atomicAdd(&deg[dst[i]], 1);
}

__global__ __launch_bounds__(1024) void scan_kernel(const int* __restrict__ deg,
                                                    int* __restrict__ offs, int n) {
    __shared__ int wsum[16];
    __shared__ int carry;
    int t = threadIdx.x;
    int lane = t & 63, w = t >> 6;
    if (t == 0) carry = 0;
    __syncthreads();
    for (int start = 0; start < n; start += 1024) {
        int i = start + t;
        int v = (i < n) ? deg[i] : 0;
        int s = v;
        #pragma unroll
        for (int d = 1; d < 64; d <<= 1) {
            int u = __shfl_up(s, d, 64);
            if (lane >= d) s += u;
        }
        if (lane == 63) wsum[w] = s;
        __syncthreads();
        int wbase = 0;
        for (int j = 0; j < w; ++j) wbase += wsum[j];
        int base = carry;
        if (i < n) offs[i] = base + wbase + s - v;
        __syncthreads();
        if (t == 1023) carry = base + wbase + s;
        __syncthreads();
    }
    if (t == 0) offs[n] = carry;
}

__global__ void fill_csr(const int* __restrict__ src, const int* __restrict__ dst,
                         const int* __restrict__ offs, int* __restrict__ cursor,
                         int* __restrict__ csr, int e) {
    int i = blockIdx.x * blockDim.x + threadIdx.x;
    if (i < e) {
        int d = dst[i];
        int pos = offs[d] + atomicAdd(&cursor[d], 1);
        csr[pos] = src[i];
    }
}

// ---------------- x -> fp16 convert ----------------

__global__ void cvt_f16(const float4* __restrict__ in, half4v* __restrict__ oh, int n4) {
    int i = blockIdx.x * blockDim.x + threadIdx.x;
    if (i >= n4) return;
    float4 v = in[i];
    half4v h;
    h[0] = (_Float16)v.x; h[1] = (_Float16)v.y;
    h[2] = (_Float16)v.z; h[3] = (_Float16)v.w;
    oh[i] = h;
}

// ---------------- fused weight prep (all 6 weights, one launch) ----------------
// W[K][dout] fp32 -> Wt[npad][K] fp16.
// NOTE: 12288 is NOT a power of two -- use subtraction, never masking (r8 bug).

__global__ void prep_all(const float* __restrict__ ws1, const float* __restrict__ wn1,
                         const float* __restrict__ ws2, const float* __restrict__ wn2,
                         const float* __restrict__ ws3, const float* __restrict__ wn3,
                         _Float16* __restrict__ o1s, _Float16* __restrict__ o1n,
                         _Float16* __restrict__ o2s, _Float16* __restrict__ o2n,
                         _Float16* __restrict__ o3c) {
    int i = blockIdx.x * blockDim.x + threadIdx.x;
    if (i < 65536) {
        const float* W = (i < 32768) ? ws1 : wn1;
        _Float16* O = (i < 32768) ? o1s : o1n;
        int j = i & 32767;                         // 32768 = 2^15, mask ok
        int nn = j >> 7, k = j & 127;              // K=128, dout=256
        O[j] = (_Float16)W[k * 256 + nn];
    } else if (i < 196608) {
        int j = i - 65536;
        const float* W = (j < 65536) ? ws2 : wn2;
        _Float16* O = (j < 65536) ? o2s : o2n;
        j &= 65535;                                // 65536 = 2^16, mask ok
        int nn = j >> 8, k = j & 255;              // K=256, dout=256
        O[j] = (_Float16)W[k * 256 + nn];
    } else if (i < 221184) {
        int j = i - 196608;                        // [0, 24576)
        const float* W = (j < 12288) ? ws3 : wn3;
        _Float16* O = o3c + ((j < 12288) ? 0 : 12288);
        j = (j < 12288) ? j : j - 12288;           // FIX: 12288 not pow2, subtract
        int nn = j >> 8, k = j & 255;              // K=256, dout=47, npad=48
        O[j] = (nn < 47) ? (_Float16)W[k * 47 + nn] : (_Float16)0.f;
    }
}

// ---------------- mean aggregation (fp16 gather, fp32 accumulate, fp16 out) ----------
// Multi-row gathers: sub-wave groups each fetch a DIFFERENT edge's row per
// iteration (16 B/lane dwordx4), so one VMEM instruction covers 2-4 rows.
// Cross-group combine via __shfl_xor AFTER the loop (no in-loop shfl).

// D=256: wave per node; half-waves handle edges e, e+1; 16 B/lane.
__global__ __launch_bounds__(256) void agg256h(const _Float16* __restrict__ Hh,
                                               const int* __restrict__ csr,
                                               const int* __restrict__ offs,
                                               _Float16* __restrict__ Ph, int n) {
    int node = blockIdx.x * 4 + (threadIdx.x >> 6);
    int lane = threadIdx.x & 63;
    int hf = lane >> 5;
    int sl = lane & 31;
    if (node >= n) return;
    int e0 = offs[node], e1 = offs[node + 1];
    float a[8] = {0.f, 0.f, 0.f, 0.f, 0.f, 0.f, 0.f, 0.f};
    int e = e0;
    for (; e + 2 <= e1; e += 2) {
        int s = csr[e + hf];
        half8 u = ((const half8*)(Hh + (size_t)s * 256))[sl];
        #pragma unroll
        for (int j = 0; j < 8; ++j) a[j] += (float)u[j];
    }
    if (e < e1 && hf == 0) {
        int s = csr[e];
        half8 u = ((const half8*)(Hh + (size_t)s * 256))[sl];
        #pragma unroll
        for (int j = 0; j < 8; ++j) a[j] += (float)u[j];
    }
    #pragma unroll
    for (int j = 0; j < 8; ++j) a[j] += __shfl_xor(a[j], 32);
    if (hf == 0) {
        float inv = 1.0f / fmaxf((float)(e1 - e0), 1.0f);
        half8 rh;
        #pragma unroll
        for (int j = 0; j < 8; ++j) rh[j] = (_Float16)(a[j] * inv);
        ((half8*)(Ph + (size_t)node * 256))[sl] = rh;
    }
}

// D=128: wave per node; quarter-waves handle edges e..e+3; 16 B/lane.
__global__ __launch_bounds__(256) void agg128h(const _Float16* __restrict__ xh,
                                               const int* __restrict__ csr,
                                               const int* __restrict__ offs,
                                               _Float16* __restrict__ Ph, int n) {
    int node = blockIdx.x * 4 + (threadIdx.x >> 6);
    int lane = threadIdx.x & 63;
    int qtr = lane >> 4;
    int sl = lane & 15;
    if (node >= n) return;
    int e0 = offs[node], e1 = offs[node + 1];
    float a[8] = {0.f, 0.f, 0.f, 0.f, 0.f, 0.f, 0.f, 0.f};
    int e = e0;
    for (; e + 4 <= e1; e += 4) {
        int s = csr[e + qtr];
        half8 u = ((const half8*)(xh + (size_t)s * 128))[sl];
        #pragma unroll
        for (int j = 0; j < 8; ++j) a[j] += (float)u[j];
    }
    int rem = e1 - e;
    if (qtr < rem) {
        int s = csr[e + qtr];
        half8 u = ((const half8*)(xh + (size_t)s * 128))[sl];
        #pragma unroll
        for (int j = 0; j < 8; ++j) a[j] += (float)u[j];
    }
    #pragma unroll
    for (int j = 0; j < 8; ++j) {
        a[j] += __shfl_xor(a[j], 16);
        a[j] += __shfl_xor(a[j], 32);
    }
    if (lane < 16) {
        float inv = 1.0f / fmaxf((float)(e1 - e0), 1.0f);
        half8 rh;
        #pragma unroll
        for (int j = 0; j < 8; ++j) rh[j] = (_Float16)(a[j] * inv);
        ((half8*)(Ph + (size_t)node * 128))[sl] = rh;
    }
}

// Layer-3 finish: out[node][0:47] = S[node] + mean(Y[nbrs]); wave per node,
// quarter-waves handle 4 edges/iter; Y rows 96 B fp16.
__global__ __launch_bounds__(256) void agg_l3(const _Float16* __restrict__ Y,
                                              const float* __restrict__ S,
                                              const int* __restrict__ csr,
                                              const int* __restrict__ offs,
                                              float* __restrict__ out, int n) {
    int node = blockIdx.x * 4 + (threadIdx.x >> 6);
    int lane = threadIdx.x & 63;
    int qtr = lane >> 4;
    int sl = lane & 15;
    int c = sl < 12 ? sl : 11;
    if (node >= n) return;
    int e0 = offs[node], e1 = offs[node + 1];
    float a0 = 0.f, a1 = 0.f, a2 = 0.f, a3 = 0.f;
    int e = e0;
    for (; e + 4 <= e1; e += 4) {
        int s = csr[e + qtr];
        half4v f = ((const half4v*)(Y + (size_t)s * 48))[c];
        a0 += (float)f[0]; a1 += (float)f[1]; a2 += (float)f[2]; a3 += (float)f[3];
    }
    int rem = e1 - e;
    if (qtr < rem) {
        int s = csr[e + qtr];
        half4v f = ((const half4v*)(Y + (size_t)s * 48))[c];
        a0 += (float)f[0]; a1 += (float)f[1]; a2 += (float)f[2]; a3 += (float)f[3];
    }
    a0 += __shfl_xor(a0, 16); a0 += __shfl_xor(a0, 32);
    a1 += __shfl_xor(a1, 16); a1 += __shfl_xor(a1, 32);
    a2 += __shfl_xor(a2, 16); a2 += __shfl_xor(a2, 32);
    a3 += __shfl_xor(a3, 16); a3 += __shfl_xor(a3, 32);
    if (lane < 12) {
        float inv = 1.0f / fmaxf((float)(e1 - e0), 1.0f);
        float4 sv = ((const float4*)(S + (size_t)node * 48))[c];
        float r[4] = {sv.x + a0 * inv, sv.y + a1 * inv, sv.z + a2 * inv, sv.w + a3 * inv};
        #pragma unroll
        for (int k = 0; k < 4; ++k) {
            int col = c * 4 + k;
            if (col < 47) out[(size_t)node * 47 + col] = r[k];
        }
    }
}

// ---------------- MFMA GEMM (plain fp16, A direct-from-global) -------------
// out[128 x dout] = A1@W1 (+ A2@W2) + b (+relu), fp32 accumulate.
// Each wave owns rows [bm+w*32, bm+w*32+32): A frags are direct 16B global loads
// (no A staging; in-place layer 2 safe). B staged in LDS (LDT=36, conflict-free)
// with register prefetch of step s+1 issued after the barrier.
// OUTFMT 1: fp16 H write (dout=256). OUTFMT 2: cols 0-47 -> S fp32 (+bias),
// cols 48-95 -> Y fp16 (stride 48).

template <int NTILES, int OUTFMT>
__global__ __launch_bounds__(256, 2) void gemm_mfma(
    const _Float16* __restrict__ A1h, const _Float16* __restrict__ A2h,
    const _Float16* __restrict__ W1, const _Float16* __restrict__ W2,
    const float* __restrict__ bias, float* __restrict__ outS, _Float16* __restrict__ outY,
    _Float16* __restrict__ outh, int n, int K, int dout, int relu, int phases) {
    constexpr int NPAD = NTILES * 16;
    constexpr int LDT = 36;
    __shared__ _Float16 Bs[NPAD * LDT];

    const int t = threadIdx.x;
    const int bm = blockIdx.x * 128;
    const int lane = t & 63;
    const int w = t >> 6;
    const int quad = lane >> 4;
    const int tl = lane & 15;
    const int r0 = bm + w * 32 + tl;
    const int r1 = r0 + 16;

    floatx4 acc[2][NTILES];
    #pragma unroll
    for (int i = 0; i < 2; ++i)
        #pragma unroll
        for (int j = 0; j < NTILES; ++j) acc[i][j] = (floatx4){0.f, 0.f, 0.f, 0.f};

    const int spp = K >> 5;
    const int nsteps = phases * spp;

    half8 pb0, pb1, pb2, pb3;
    half8 pah0 = {0}, pah1 = {0};

    if (t < NPAD) {
        const half8* p = (const half8*)(W1 + (size_t)t * K);
        pb0 = p[0]; pb1 = p[1]; pb2 = p[2]; pb3 = p[3];
    }
    {
        int kq = quad * 8;
        if (r0 < n) pah0 = *(const half8*)(A1h + (size_t)r0 * K + kq);
        if (r1 < n) pah1 = *(const half8*)(A1h + (size_t)r1 * K + kq);
    }

    for (int s = 0; s < nsteps; ++s) {
        __syncthreads();
        if (t < NPAD) {
            *(half8*)&Bs[t * LDT + 0]  = pb0;
            *(half8*)&Bs[t * LDT + 8]  = pb1;
            *(half8*)&Bs[t * LDT + 16] = pb2;
            *(half8*)&Bs[t * LDT + 24] = pb3;
        }
        __syncthreads();
        half8 ah0 = pah0, ah1 = pah1;
        if (s + 1 < nsteps) {
            int s2 = s + 1;
            int ph2 = (s2 >= spp) ? 1 : 0;
            int k02 = (ph2 ? s2 - spp : s2) << 5;
            if (t < NPAD) {
                const _Float16* W = ph2 ? W2 : W1;
                const half8* p = (const half8*)(W + (size_t)t * K + k02);
                pb0 = p[0]; pb1 = p[1]; pb2 = p[2]; pb3 = p[3];
            }
            const _Float16* Ah = ph2 ? A2h : A1h;
            int kq = k02 + quad * 8;
            pah0 = (half8){0}; pah1 = (half8){0};
            if (r0 < n) pah0 = *(const half8*)(Ah + (size_t)r0 * K + kq);
            if (r1 < n) pah1 = *(const half8*)(Ah + (size_t)r1 * K + kq);
        }
        #pragma unroll
        for (int nt = 0; nt < NTILES; ++nt) {
            half8 bh = *(const half8*)&Bs[(nt * 16 + tl) * LDT + quad * 8];
            acc[0][nt] = __builtin_amdgcn_mfma_f32_16x16x32_f16(ah0, bh, acc[0][nt], 0, 0, 0);
            acc[1][nt] = __builtin_amdgcn_mfma_f32_16x16x32_f16(ah1, bh, acc[1][nt], 0, 0, 0);
        }
    }

    #pragma unroll
    for (int mt = 0; mt < 2; ++mt) {
        #pragma unroll
        for (int nt = 0; nt < NTILES; ++nt) {
            int gc = nt * 16 + tl;
            if (OUTFMT == 1 && gc >= dout) continue;
            #pragma unroll
            for (int r = 0; r < 4; ++r) {
                int gr = bm + w * 32 + mt * 16 + quad * 4 + r;
                if (gr >= n) continue;
                float v = acc[mt][nt][r];
                if (OUTFMT == 1) {
                    v += bias[gc];
                    if (relu) v = fmaxf(v, 0.f);
                    outh[(size_t)gr * 256 + gc] = (_Float16)v;
                } else {
                    if (gc < 48) {
                        v += (gc < 47) ? bias[gc] : 0.f;
                        outS[(size_t)gr * 48 + gc] = v;
                    } else {
                        outY[(size_t)gr * 48 + (gc - 48)] = (_Float16)v;
                    }
                }
            }
        }
    }
}

extern "C" void kernel_launch(void* const* d_in, const int* in_sizes, int n_in,
                              void* d_out, int out_size, void* d_ws, size_t ws_size,
                              hipStream_t stream) {
    (void)in_sizes; (void)n_in; (void)out_size; (void)ws_size;
    const int N = N_NODES, E = N_EDGES;
    const float* x = (const float*)d_in[0];
    const int* src = (const int*)d_in[1];
    const int* dst = (const int*)d_in[2];
    const float* w_self1 = (const float*)d_in[3];
    const float* w_neigh1 = (const float*)d_in[4];
    const float* b1 = (const float*)d_in[5];
    const float* w_self2 = (const float*)d_in[6];
    const float* w_neigh2 = (const float*)d_in[7];
    const float* b2 = (const float*)d_in[8];
    const float* w_self3 = (const float*)d_in[9];
    const float* w_neigh3 = (const float*)d_in[10];
    const float* b3 = (const float*)d_in[11];
    float* out = (float*)d_out;

    // workspace layout (~110 MB)
    _Float16* Ph = (_Float16*)d_ws;             // N*256 fp16 (agg; N*128 in L1)
    _Float16* Hh = Ph + (size_t)N * 256;        // N*256 fp16 (hidden)
    int* deg = (int*)(Hh + (size_t)N * 256);    // N (reused as cursor)
    int* offs = deg + N;                        // N+4
    int* csr = offs + N + 4;                    // E
    _Float16* wbuf = (_Float16*)(csr + E);
    _Float16* w1s = wbuf;                       // 256*128
    _Float16* w1n = w1s + 32768;                // 256*128
    _Float16* w2s = w1n + 32768;                // 256*256
    _Float16* w2n = w2s + 65536;                // 256*256
    _Float16* w3c = w2n + 65536;                // 96*256 combined [self|neigh]
    // overlays on the Ph region:
    _Float16* xh = Ph + (size_t)N * 128;        // N*128 fp16 (layer 1, upper half)
    float* S = (float*)Ph;                      // N*48 fp32 (layer 3; P dead)
    _Float16* Y = (_Float16*)(S + (size_t)N * 48);  // N*48 fp16

    hipMemsetAsync(deg, 0, N * sizeof(int), stream);
    deg_kernel<<<(E + 255) / 256, 256, 0, stream>>>(dst, deg, E);
    scan_kernel<<<1, 1024, 0, stream>>>(deg, offs, N);
    hipMemsetAsync(deg, 0, N * sizeof(int), stream);
    fill_csr<<<(E + 255) / 256, 256, 0, stream>>>(src, dst, offs, deg, csr, E);

    cvt_f16<<<(N * 128 / 4 + 255) / 256, 256, 0, stream>>>((const float4*)x, (half4v*)xh,
                                                           N * 128 / 4);
    prep_all<<<(221184 + 255) / 256, 256, 0, stream>>>(w_self1, w_neigh1, w_self2, w_neigh2,
                                                       w_self3, w_neigh3, w1s, w1n, w2s, w2n,
                                                       w3c);

    int gemmGrid = (N + 127) / 128;
    int aggGrid = (N + 3) / 4;

    // layer 1: 128 -> 256, relu.  Hh = fp16(relu(x@Ws1 + P@Wn1 + b1))
    agg128h<<<aggGrid, 256, 0, stream>>>(xh, csr, offs, Ph, N);
    gemm_mfma<16, 1><<<gemmGrid, 256, 0, stream>>>(xh, Ph, w1s, w1n, b1, nullptr, nullptr,
                                                   Hh, N, 128, 256, 1, 2);
    // layer 2: 256 -> 256, relu.  Hh = fp16(relu(H@Ws2 + P@Wn2 + b2))  (in place)
    agg256h<<<aggGrid, 256, 0, stream>>>(Hh, csr, offs, Ph, N);
    gemm_mfma<16, 1><<<gemmGrid, 256, 0, stream>>>(Hh, Ph, w2s, w2n, b2, nullptr, nullptr,
                                                   Hh, N, 256, 256, 1, 2);
    // layer 3: S = H@Ws3+b3 (fp32), Y = H@Wn3 (fp16) in one dual GEMM, then
    // out = S + mean-agg(Y).
    gemm_mfma<6, 2><<<gemmGrid, 256, 0, stream>>>(Hh, nullptr, w3c, nullptr, b3, S, Y,
                                                  nullptr, N, 256, 96, 0, 1);
    agg_l3<<<aggGrid, 256, 0, stream>>>(Y, S, csr, offs, out, N);
}